// Round 1
// baseline (529.068 us; speedup 1.0000x reference)
//
#include <hip/hip_runtime.h>
#include <math.h>

#define NEG_SLOPE 0.2f

// ---------------- GEMM: h = x @ W^T, fused s/d logit reduction ----------------
// 128 threads/block (2 waves). Thread t owns output column t (= head*16+dim).
// W[t][0..127] lives in 128 VGPRs. x row address is uniform -> scalar loads.
__global__ __launch_bounds__(128) void gat_gemm(
    const float* __restrict__ x, const float* __restrict__ W,
    const float* __restrict__ srcA, const float* __restrict__ dstA,
    float* __restrict__ h, float* __restrict__ s, float* __restrict__ dv, int N)
{
  const int col = threadIdx.x;  // 0..127
  float4 w[32];
  const float4* Wv = (const float4*)(W + (size_t)col * 128);
#pragma unroll
  for (int i = 0; i < 32; ++i) w[i] = Wv[i];
  const float sa = srcA[col];
  const float da = dstA[col];

  for (int row = blockIdx.x; row < N; row += gridDim.x) {
    const float4* xv = (const float4*)(x + (size_t)row * 128);
    float acc = 0.f;
#pragma unroll
    for (int i = 0; i < 32; ++i) {
      float4 xx = xv[i];
      acc = fmaf(xx.x, w[i].x, acc);
      acc = fmaf(xx.y, w[i].y, acc);
      acc = fmaf(xx.z, w[i].z, acc);
      acc = fmaf(xx.w, w[i].w, acc);
    }
    h[(size_t)row * 128 + col] = acc;
    // per-head dot with attention vectors: reduce within 16-lane groups
    float ss = acc * sa, dd = acc * da;
#pragma unroll
    for (int off = 1; off < 16; off <<= 1) {
      ss += __shfl_xor(ss, off, 64);
      dd += __shfl_xor(dd, off, 64);
    }
    if ((col & 15) == 0) {
      s[(size_t)row * 8 + (col >> 4)]  = ss;
      dv[(size_t)row * 8 + (col >> 4)] = dd;
    }
  }
}

// ---------------- int64-vs-int32 edge-index detection ----------------
// If edges are int64 (little-endian, values < 2^31), every odd 32-bit word of
// the row array is 0. With int32 data those words are random row ids.
__global__ void gat_detect(const int* __restrict__ ei, int E, int* __restrict__ flag)
{
  __shared__ int any;
  if (threadIdx.x == 0) any = 0;
  __syncthreads();
  int n = E < 512 ? E : 512;
  int local = 0;
  for (int i = threadIdx.x; i < n; i += 256)
    if (ei[2 * i + 1] != 0) local = 1;
  if (local) atomicOr(&any, 1);
  __syncthreads();
  if (threadIdx.x == 0) *flag = (any == 0) ? 1 : 0;  // 1 => int64 layout
}

// ---------------- histogram of destination rows ----------------
__global__ __launch_bounds__(256) void gat_hist(
    const int* __restrict__ ei, int E, const int* __restrict__ flag, int* __restrict__ count)
{
  const int is64 = *flag;
  int i = blockIdx.x * 256 + threadIdx.x;
  const int stride = gridDim.x * 256;
  for (; i < E; i += stride) {
    int r = is64 ? ei[2 * i] : ei[i];
    atomicAdd(&count[r], 1);
  }
}

// ---------------- 2-level exclusive scan of (count[n] + 1) ----------------
__global__ __launch_bounds__(256) void gat_scan_part(
    const int* __restrict__ count, int N, int* __restrict__ partial)
{
  __shared__ int sm[256];
  int base = blockIdx.x * 1024;
  int tsum = 0;
  for (int i = threadIdx.x; i < 1024; i += 256) {
    int idx = base + i;
    if (idx < N) tsum += count[idx] + 1;  // +1 = self loop
  }
  sm[threadIdx.x] = tsum;
  __syncthreads();
  for (int off = 128; off > 0; off >>= 1) {
    if (threadIdx.x < off) sm[threadIdx.x] += sm[threadIdx.x + off];
    __syncthreads();
  }
  if (threadIdx.x == 0) partial[blockIdx.x] = sm[0];
}

__global__ __launch_bounds__(1024) void gat_scan_mid(int* __restrict__ partial, int nb)
{
  __shared__ int sm[1024];
  int t = threadIdx.x;
  int v = (t < nb) ? partial[t] : 0;
  sm[t] = v;
  __syncthreads();
  int acc = v;
  for (int off = 1; off < 1024; off <<= 1) {
    int other = (t >= off) ? sm[t - off] : 0;
    __syncthreads();
    acc += other;
    sm[t] = acc;
    __syncthreads();
  }
  if (t < nb) partial[t] = acc - v;  // exclusive
}

__global__ __launch_bounds__(256) void gat_scan_final(
    const int* __restrict__ count, int N, const int* __restrict__ partial,
    int* __restrict__ offsets, int* __restrict__ cursor, int total)
{
  __shared__ int sm[256];
  int base = blockIdx.x * 1024 + threadIdx.x * 4;
  int v[4];
  int tsum = 0;
#pragma unroll
  for (int j = 0; j < 4; ++j) {
    int idx = base + j;
    v[j] = (idx < N) ? (count[idx] + 1) : 0;
    tsum += v[j];
  }
  sm[threadIdx.x] = tsum;
  __syncthreads();
  int acc = tsum;
  for (int off = 1; off < 256; off <<= 1) {
    int other = (threadIdx.x >= off) ? sm[threadIdx.x - off] : 0;
    __syncthreads();
    acc += other;
    sm[threadIdx.x] = acc;
    __syncthreads();
  }
  int ex = acc - tsum + partial[blockIdx.x];
#pragma unroll
  for (int j = 0; j < 4; ++j) {
    int idx = base + j;
    if (idx < N) { offsets[idx] = ex; cursor[idx] = ex; ex += v[j]; }
  }
  if (blockIdx.x == 0 && threadIdx.x == 0) offsets[N] = total;
}

// ---------------- scatter col indices into row-sorted order ----------------
__global__ __launch_bounds__(256) void gat_scatter(
    const int* __restrict__ ei, int E, int N, const int* __restrict__ flag,
    int* __restrict__ cursor, int* __restrict__ scol)
{
  const int is64 = *flag;
  int i = blockIdx.x * 256 + threadIdx.x;
  const int stride = gridDim.x * 256;
  const int total = E + N;
  for (; i < total; i += stride) {
    int r, c;
    if (i < E) {
      if (is64) { r = ei[2 * i]; c = ei[2 * (E + i)]; }
      else      { r = ei[i];     c = ei[E + i]; }
    } else {
      r = i - E; c = r;  // self loop
    }
    int pos = atomicAdd(&cursor[r], 1);
    scol[pos] = c;
  }
}

// ---------------- per-row online softmax + SpMM, one wave per row ----------------
// lane = head*8 + pair; lane owns out[row, lane*2 .. lane*2+1] (float2, coalesced)
__global__ __launch_bounds__(256) void gat_agg(
    const float* __restrict__ h, const float* __restrict__ s, const float* __restrict__ dv,
    const int* __restrict__ offsets, const int* __restrict__ scol,
    float* __restrict__ out, int N)
{
  int wid = (int)((blockIdx.x * 256 + threadIdx.x) >> 6);
  int lane = threadIdx.x & 63;
  if (wid >= N) return;
  const int head = lane >> 3;
  const int beg = offsets[wid];
  const int end = offsets[wid + 1];
  const float sl = s[(size_t)wid * 8 + head];

  float m = -INFINITY, z = 0.f, ax = 0.f, ay = 0.f;
  for (int i = beg; i < end; ++i) {
    int c = scol[i];
    float dl = dv[(size_t)c * 8 + head];
    const float2 hv = *(const float2*)(h + (size_t)c * 128 + lane * 2);
    float e = sl + dl;
    e = (e > 0.f) ? e : NEG_SLOPE * e;
    float mn = fmaxf(m, e);
    float sc  = __expf(m - mn);   // first iter: exp(-inf) = 0
    float wgt = __expf(e - mn);
    z  = z * sc + wgt;
    ax = ax * sc + wgt * hv.x;
    ay = ay * sc + wgt * hv.y;
    m = mn;
  }
  float inv = 1.f / z;
  *(float2*)(out + (size_t)wid * 128 + lane * 2) = make_float2(ax * inv, ay * inv);
}

extern "C" void kernel_launch(void* const* d_in, const int* in_sizes, int n_in,
                              void* d_out, int out_size, void* d_ws, size_t ws_size,
                              hipStream_t stream) {
  const float* x    = (const float*)d_in[0];
  const int*   ei   = (const int*)d_in[1];
  const float* W    = (const float*)d_in[2];
  const float* srcA = (const float*)d_in[3];
  const float* dstA = (const float*)d_in[4];
  float* out = (float*)d_out;
  const int N = in_sizes[0] / 128;
  const int E = in_sizes[1] / 2;

  // workspace layout
  float* h  = (float*)d_ws;                    // N*128
  float* s  = h + (size_t)N * 128;             // N*8
  float* dv = s + (size_t)N * 8;               // N*8
  int* count   = (int*)(dv + (size_t)N * 8);   // N
  int* offsets = count + N;                    // N+1
  int* cursor  = offsets + (N + 1);            // N
  int* partial = cursor + N;                   // 1024
  int* flag    = partial + 1024;               // 4 (padded)
  int* scol    = flag + 4;                     // E+N

  hipMemsetAsync(count, 0, (size_t)N * sizeof(int), stream);
  gat_gemm<<<4096, 128, 0, stream>>>(x, W, srcA, dstA, h, s, dv, N);
  gat_detect<<<1, 256, 0, stream>>>(ei, E, flag);
  gat_hist<<<2048, 256, 0, stream>>>(ei, E, flag, count);
  const int nb = (N + 1023) / 1024;
  gat_scan_part<<<nb, 256, 0, stream>>>(count, N, partial);
  gat_scan_mid<<<1, 1024, 0, stream>>>(partial, nb);
  gat_scan_final<<<nb, 256, 0, stream>>>(count, N, partial, offsets, cursor, E + N);
  gat_scatter<<<2048, 256, 0, stream>>>(ei, E, N, flag, cursor, scol);
  gat_agg<<<(N + 3) / 4, 256, 0, stream>>>(h, s, dv, offsets, scol, out, N);
}

// Round 3
// 478.420 us; speedup vs baseline: 1.1059x; 1.1059x over previous
//
#include <hip/hip_runtime.h>
#include <hip/hip_bf16.h>
#include <math.h>

#define NEG_SLOPE 0.2f

// ---------------- GEMM: h = x @ W^T (bf16 out), fused s/d logit reduction ----
// 128 threads/block (2 waves). Thread t owns output column t (= head*16+dim).
// W[t][0..127] lives in 128 VGPRs. x row address is uniform per wave.
__global__ __launch_bounds__(128) void gat_gemm(
    const float* __restrict__ x, const float* __restrict__ W,
    const float* __restrict__ srcA, const float* __restrict__ dstA,
    ushort* __restrict__ hb, float* __restrict__ s, float* __restrict__ dv, int N)
{
  const int col = threadIdx.x;  // 0..127
  float4 w[32];
  const float4* Wv = (const float4*)(W + (size_t)col * 128);
#pragma unroll
  for (int i = 0; i < 32; ++i) w[i] = Wv[i];
  const float sa = srcA[col];
  const float da = dstA[col];

  for (int row = blockIdx.x; row < N; row += gridDim.x) {
    const float4* xv = (const float4*)(x + (size_t)row * 128);
    float acc = 0.f;
#pragma unroll
    for (int i = 0; i < 32; ++i) {
      float4 xx = xv[i];
      acc = fmaf(xx.x, w[i].x, acc);
      acc = fmaf(xx.y, w[i].y, acc);
      acc = fmaf(xx.z, w[i].z, acc);
      acc = fmaf(xx.w, w[i].w, acc);
    }
    hb[(size_t)row * 128 + col] = __bfloat16_as_ushort(__float2bfloat16(acc));
    // per-head dot with attention vectors: reduce within 16-lane groups
    float ss = acc * sa, dd = acc * da;
#pragma unroll
    for (int off = 1; off < 16; off <<= 1) {
      ss += __shfl_xor(ss, off, 64);
      dd += __shfl_xor(dd, off, 64);
    }
    if ((col & 15) == 0) {
      s[(size_t)row * 8 + (col >> 4)]  = ss;
      dv[(size_t)row * 8 + (col >> 4)] = dd;
    }
  }
}

// ---------------- int64-vs-int32 edge-index detection ----------------
__global__ void gat_detect(const int* __restrict__ ei, int E, int* __restrict__ flag)
{
  __shared__ int any;
  if (threadIdx.x == 0) any = 0;
  __syncthreads();
  int n = E < 512 ? E : 512;
  int local = 0;
  for (int i = threadIdx.x; i < n; i += 256)
    if (ei[2 * i + 1] != 0) local = 1;
  if (local) atomicOr(&any, 1);
  __syncthreads();
  if (threadIdx.x == 0) *flag = (any == 0) ? 1 : 0;  // 1 => int64 layout
}

// ---------------- histogram of destination rows ----------------
__global__ __launch_bounds__(256) void gat_hist(
    const int* __restrict__ ei, int E, const int* __restrict__ flag, int* __restrict__ count)
{
  const int is64 = *flag;
  int i = blockIdx.x * 256 + threadIdx.x;
  const int stride = gridDim.x * 256;
  for (; i < E; i += stride) {
    int r = is64 ? ei[2 * i] : ei[i];
    atomicAdd(&count[r], 1);
  }
}

// ---------------- 2-level exclusive scan of (count[n] + 1) ----------------
__global__ __launch_bounds__(256) void gat_scan_part(
    const int* __restrict__ count, int N, int* __restrict__ partial)
{
  __shared__ int sm[256];
  int base = blockIdx.x * 1024;
  int tsum = 0;
  for (int i = threadIdx.x; i < 1024; i += 256) {
    int idx = base + i;
    if (idx < N) tsum += count[idx] + 1;  // +1 = self loop
  }
  sm[threadIdx.x] = tsum;
  __syncthreads();
  for (int off = 128; off > 0; off >>= 1) {
    if (threadIdx.x < off) sm[threadIdx.x] += sm[threadIdx.x + off];
    __syncthreads();
  }
  if (threadIdx.x == 0) partial[blockIdx.x] = sm[0];
}

__global__ __launch_bounds__(1024) void gat_scan_mid(int* __restrict__ partial, int nb)
{
  __shared__ int sm[1024];
  int t = threadIdx.x;
  int v = (t < nb) ? partial[t] : 0;
  sm[t] = v;
  __syncthreads();
  int acc = v;
  for (int off = 1; off < 1024; off <<= 1) {
    int other = (t >= off) ? sm[t - off] : 0;
    __syncthreads();
    acc += other;
    sm[t] = acc;
    __syncthreads();
  }
  if (t < nb) partial[t] = acc - v;  // exclusive
}

__global__ __launch_bounds__(256) void gat_scan_final(
    const int* __restrict__ count, int N, const int* __restrict__ partial,
    int* __restrict__ offsets, int* __restrict__ cursor, int total)
{
  __shared__ int sm[256];
  int base = blockIdx.x * 1024 + threadIdx.x * 4;
  int v[4];
  int tsum = 0;
#pragma unroll
  for (int j = 0; j < 4; ++j) {
    int idx = base + j;
    v[j] = (idx < N) ? (count[idx] + 1) : 0;
    tsum += v[j];
  }
  sm[threadIdx.x] = tsum;
  __syncthreads();
  int acc = tsum;
  for (int off = 1; off < 256; off <<= 1) {
    int other = (threadIdx.x >= off) ? sm[threadIdx.x - off] : 0;
    __syncthreads();
    acc += other;
    sm[threadIdx.x] = acc;
    __syncthreads();
  }
  int ex = acc - tsum + partial[blockIdx.x];
#pragma unroll
  for (int j = 0; j < 4; ++j) {
    int idx = base + j;
    if (idx < N) { offsets[idx] = ex; cursor[idx] = ex; ex += v[j]; }
  }
  if (blockIdx.x == 0 && threadIdx.x == 0) offsets[N] = total;
}

// ---------------- scatter col indices into row-sorted order ----------------
__global__ __launch_bounds__(256) void gat_scatter(
    const int* __restrict__ ei, int E, int N, const int* __restrict__ flag,
    int* __restrict__ cursor, int* __restrict__ scol)
{
  const int is64 = *flag;
  int i = blockIdx.x * 256 + threadIdx.x;
  const int stride = gridDim.x * 256;
  const int total = E + N;
  for (; i < total; i += stride) {
    int r, c;
    if (i < E) {
      if (is64) { r = ei[2 * i]; c = ei[2 * (E + i)]; }
      else      { r = ei[i];     c = ei[E + i]; }
    } else {
      r = i - E; c = r;  // self loop
    }
    int pos = atomicAdd(&cursor[r], 1);
    scol[pos] = c;
  }
}

// ---------------- per-row online softmax + SpMM, one wave per row ----------------
// h is bf16-packed: row stride 64 uints (128 bf16). lane owns elems 2*lane,2*lane+1.
__global__ __launch_bounds__(256) void gat_agg(
    const uint* __restrict__ hb, const float* __restrict__ s, const float* __restrict__ dv,
    const int* __restrict__ offsets, const int* __restrict__ scol,
    float* __restrict__ out, int N)
{
  int wid = (int)((blockIdx.x * 256 + threadIdx.x) >> 6);
  int lane = threadIdx.x & 63;
  if (wid >= N) return;
  const int head = lane >> 3;
  const int beg = offsets[wid];
  const int end = offsets[wid + 1];
  const float sl = s[(size_t)wid * 8 + head];

  // 2-deep software pipeline: scol 2 ahead, gathers 1 ahead
  int c1 = scol[beg];                                  // col for iter i
  int c2 = (beg + 1 < end) ? scol[beg + 1] : c1;       // col for iter i+1
  float dl0 = dv[(size_t)c1 * 8 + head];
  uint  hu0 = hb[(size_t)c1 * 64 + lane];

  float m = -INFINITY, z = 0.f, ax = 0.f, ay = 0.f;
  for (int i = beg; i < end; ++i) {
    int c3 = (i + 2 < end) ? scol[i + 2] : c2;
    float dl1 = dv[(size_t)c2 * 8 + head];
    uint  hu1 = hb[(size_t)c2 * 64 + lane];

    float hx = __uint_as_float(hu0 << 16);
    float hy = __uint_as_float(hu0 & 0xFFFF0000u);
    float e = sl + dl0;
    e = (e > 0.f) ? e : NEG_SLOPE * e;
    float mn = fmaxf(m, e);
    float sc  = __expf(m - mn);   // first iter: exp(-inf) = 0
    float wgt = __expf(e - mn);
    z  = z * sc + wgt;
    ax = ax * sc + wgt * hx;
    ay = ay * sc + wgt * hy;
    m = mn;

    c2 = c3; dl0 = dl1; hu0 = hu1;
  }
  float inv = 1.f / z;
  *(float2*)(out + (size_t)wid * 128 + lane * 2) = make_float2(ax * inv, ay * inv);
}

extern "C" void kernel_launch(void* const* d_in, const int* in_sizes, int n_in,
                              void* d_out, int out_size, void* d_ws, size_t ws_size,
                              hipStream_t stream) {
  const float* x    = (const float*)d_in[0];
  const int*   ei   = (const int*)d_in[1];
  const float* W    = (const float*)d_in[2];
  const float* srcA = (const float*)d_in[3];
  const float* dstA = (const float*)d_in[4];
  float* out = (float*)d_out;
  const int N = in_sizes[0] / 128;
  const int E = in_sizes[1] / 2;

  // workspace layout
  ushort* hbuf = (ushort*)d_ws;                       // N*128 bf16
  float* s  = (float*)(hbuf + (size_t)N * 128);       // N*8
  float* dv = s + (size_t)N * 8;                      // N*8
  int* count   = (int*)(dv + (size_t)N * 8);          // N
  int* offsets = count + N;                           // N+1
  int* cursor  = offsets + (N + 1);                   // N
  int* partial = cursor + N;                          // 1024
  int* flag    = partial + 1024;                      // 4 (padded)
  int* scol    = flag + 4;                            // E+N

  (void)hipMemsetAsync(count, 0, (size_t)N * sizeof(int), stream);
  gat_gemm<<<4096, 128, 0, stream>>>(x, W, srcA, dstA, hbuf, s, dv, N);
  gat_detect<<<1, 256, 0, stream>>>(ei, E, flag);
  gat_hist<<<2048, 256, 0, stream>>>(ei, E, flag, count);
  const int nb = (N + 1023) / 1024;
  gat_scan_part<<<nb, 256, 0, stream>>>(count, N, partial);
  gat_scan_mid<<<1, 1024, 0, stream>>>(partial, nb);
  gat_scan_final<<<nb, 256, 0, stream>>>(count, N, partial, offsets, cursor, E + N);
  gat_scatter<<<2048, 256, 0, stream>>>(ei, E, N, flag, cursor, scol);
  gat_agg<<<(N + 3) / 4, 256, 0, stream>>>((const uint*)hbuf, s, dv, offsets, scol, out, N);
}

// Round 4
// 371.204 us; speedup vs baseline: 1.4253x; 1.2888x over previous
//
#include <hip/hip_runtime.h>
#include <hip/hip_bf16.h>
#include <math.h>

#define NEG_SLOPE 0.2f

typedef __attribute__((ext_vector_type(8))) short short8v;
typedef __attribute__((ext_vector_type(4))) float f32x4;

// ---------------- prep: pack B fragments [W^T | W^T*Asrc | W^T*Adst] in bf16 ----
// wbf layout: frag = nt*4 + ks  (nt 0..8, ks 0..3); per frag 64 lanes x 8 bf16.
// B[k][n] for tile nt covers n = nt*16 + (lane&15), k = ks*32 + (lane>>4)*8 + j.
__global__ __launch_bounds__(256) void gat_prep(
    const float* __restrict__ W, const float* __restrict__ srcA,
    const float* __restrict__ dstA, ushort* __restrict__ wbf)
{
  int tid = blockIdx.x * 256 + threadIdx.x;  // 0..2303
  if (tid >= 36 * 64) return;
  int frag = tid >> 6, lane = tid & 63;
  int nt = frag >> 2, ks = frag & 3;
  int kbase = ks * 32 + (lane >> 4) * 8;
  ushort v[8];
  if (nt < 8) {
    int r = nt * 16 + (lane & 15);   // output col n -> W row
#pragma unroll
    for (int j = 0; j < 8; ++j)
      v[j] = __bfloat16_as_ushort(__float2bfloat16(W[(size_t)r * 128 + kbase + j]));
  } else {
    int n = lane & 15;
    int hd = n & 7;
    const float* av = (n < 8) ? srcA : dstA;
#pragma unroll
    for (int j = 0; j < 8; ++j) {
      float acc = 0.f;
      int k = kbase + j;
      for (int d = 0; d < 16; ++d)
        acc += W[(size_t)(hd * 16 + d) * 128 + k] * av[hd * 16 + d];
      v[j] = __bfloat16_as_ushort(__float2bfloat16(acc));
    }
  }
  ushort* dst = wbf + ((size_t)frag * 64 + lane) * 8;
#pragma unroll
  for (int j = 0; j < 8; ++j) dst[j] = v[j];
}

// ---------------- MFMA GEMM: [h | s | dv] = x * [W^T | Ps | Pd] ----------------
// 4 waves/block, each wave: 16 rows x 144 cols = 9 n-tiles x 4 k-steps MFMAs.
// B fragments register-resident (36 x short8v = 144 VGPR).
__global__ __launch_bounds__(256, 2) void gat_gemm_mfma(
    const float* __restrict__ x, const ushort* __restrict__ wbf,
    ushort* __restrict__ hb, float* __restrict__ s, float* __restrict__ dv,
    int N, int nchunks)
{
  const int wave = threadIdx.x >> 6, lane = threadIdx.x & 63;
  const int lrow = lane & 15, lkg = lane >> 4;

  short8v b[36];
  const short8v* wv = (const short8v*)wbf;
#pragma unroll
  for (int f = 0; f < 36; ++f) b[f] = wv[(size_t)f * 64 + lane];

  for (int chunk = blockIdx.x; chunk < nchunks; chunk += gridDim.x) {
    const int r0 = chunk * 64 + wave * 16;
    int arow = r0 + lrow; if (arow > N - 1) arow = N - 1;
    const float* xr = x + (size_t)arow * 128 + lkg * 8;

    f32x4 acc[9];
#pragma unroll
    for (int t = 0; t < 9; ++t) acc[t] = (f32x4){0.f, 0.f, 0.f, 0.f};

#pragma unroll
    for (int ks = 0; ks < 4; ++ks) {
      float4 x0 = *(const float4*)(xr + ks * 32);
      float4 x1 = *(const float4*)(xr + ks * 32 + 4);
      short8v a;
      a[0] = (short)__bfloat16_as_ushort(__float2bfloat16(x0.x));
      a[1] = (short)__bfloat16_as_ushort(__float2bfloat16(x0.y));
      a[2] = (short)__bfloat16_as_ushort(__float2bfloat16(x0.z));
      a[3] = (short)__bfloat16_as_ushort(__float2bfloat16(x0.w));
      a[4] = (short)__bfloat16_as_ushort(__float2bfloat16(x1.x));
      a[5] = (short)__bfloat16_as_ushort(__float2bfloat16(x1.y));
      a[6] = (short)__bfloat16_as_ushort(__float2bfloat16(x1.z));
      a[7] = (short)__bfloat16_as_ushort(__float2bfloat16(x1.w));
#pragma unroll
      for (int t = 0; t < 9; ++t)
        acc[t] = __builtin_amdgcn_mfma_f32_16x16x32_bf16(a, b[t * 4 + ks], acc[t], 0, 0, 0);
    }

    const int rbase = r0 + lkg * 4;  // C/D: row = (lane>>4)*4 + reg, col = lane&15
#pragma unroll
    for (int t = 0; t < 8; ++t) {
#pragma unroll
      for (int r = 0; r < 4; ++r) {
        int row = rbase + r;
        if (row < N)
          hb[(size_t)row * 128 + t * 16 + lrow] =
              __bfloat16_as_ushort(__float2bfloat16(acc[t][r]));
      }
    }
#pragma unroll
    for (int r = 0; r < 4; ++r) {
      int row = rbase + r;
      if (row < N) {
        if (lrow < 8) s[(size_t)row * 8 + lrow] = acc[8][r];
        else          dv[(size_t)row * 8 + (lrow - 8)] = acc[8][r];
      }
    }
  }
}

// ---------------- int64-vs-int32 edge-index detection ----------------
__global__ void gat_detect(const int* __restrict__ ei, int E, int* __restrict__ flag)
{
  __shared__ int any;
  if (threadIdx.x == 0) any = 0;
  __syncthreads();
  int n = E < 512 ? E : 512;
  int local = 0;
  for (int i = threadIdx.x; i < n; i += 256)
    if (ei[2 * i + 1] != 0) local = 1;
  if (local) atomicOr(&any, 1);
  __syncthreads();
  if (threadIdx.x == 0) *flag = (any == 0) ? 1 : 0;  // 1 => int64 layout
}

// ---------------- histogram of destination rows ----------------
__global__ __launch_bounds__(256) void gat_hist(
    const int* __restrict__ ei, int E, const int* __restrict__ flag, int* __restrict__ count)
{
  const int is64 = *flag;
  int i = blockIdx.x * 256 + threadIdx.x;
  const int stride = gridDim.x * 256;
  for (; i < E; i += stride) {
    int r = is64 ? ei[2 * i] : ei[i];
    atomicAdd(&count[r], 1);
  }
}

// ---------------- 2-level exclusive scan of (count[n] + 1) ----------------
__global__ __launch_bounds__(256) void gat_scan_part(
    const int* __restrict__ count, int N, int* __restrict__ partial)
{
  __shared__ int sm[256];
  int base = blockIdx.x * 1024;
  int tsum = 0;
  for (int i = threadIdx.x; i < 1024; i += 256) {
    int idx = base + i;
    if (idx < N) tsum += count[idx] + 1;  // +1 = self loop
  }
  sm[threadIdx.x] = tsum;
  __syncthreads();
  for (int off = 128; off > 0; off >>= 1) {
    if (threadIdx.x < off) sm[threadIdx.x] += sm[threadIdx.x + off];
    __syncthreads();
  }
  if (threadIdx.x == 0) partial[blockIdx.x] = sm[0];
}

__global__ __launch_bounds__(1024) void gat_scan_mid(int* __restrict__ partial, int nb)
{
  __shared__ int sm[1024];
  int t = threadIdx.x;
  int v = (t < nb) ? partial[t] : 0;
  sm[t] = v;
  __syncthreads();
  int acc = v;
  for (int off = 1; off < 1024; off <<= 1) {
    int other = (t >= off) ? sm[t - off] : 0;
    __syncthreads();
    acc += other;
    sm[t] = acc;
    __syncthreads();
  }
  if (t < nb) partial[t] = acc - v;  // exclusive
}

__global__ __launch_bounds__(256) void gat_scan_final(
    const int* __restrict__ count, int N, const int* __restrict__ partial,
    int* __restrict__ offsets, int* __restrict__ cursor, int total)
{
  __shared__ int sm[256];
  int base = blockIdx.x * 1024 + threadIdx.x * 4;
  int v[4];
  int tsum = 0;
#pragma unroll
  for (int j = 0; j < 4; ++j) {
    int idx = base + j;
    v[j] = (idx < N) ? (count[idx] + 1) : 0;
    tsum += v[j];
  }
  sm[threadIdx.x] = tsum;
  __syncthreads();
  int acc = tsum;
  for (int off = 1; off < 256; off <<= 1) {
    int other = (threadIdx.x >= off) ? sm[threadIdx.x - off] : 0;
    __syncthreads();
    acc += other;
    sm[threadIdx.x] = acc;
    __syncthreads();
  }
  int ex = acc - tsum + partial[blockIdx.x];
#pragma unroll
  for (int j = 0; j < 4; ++j) {
    int idx = base + j;
    if (idx < N) { offsets[idx] = ex; cursor[idx] = ex; ex += v[j]; }
  }
  if (blockIdx.x == 0 && threadIdx.x == 0) offsets[N] = total;
}

// ---------------- scatter col indices into row-sorted order ----------------
__global__ __launch_bounds__(256) void gat_scatter(
    const int* __restrict__ ei, int E, int N, const int* __restrict__ flag,
    int* __restrict__ cursor, int* __restrict__ scol)
{
  const int is64 = *flag;
  int i = blockIdx.x * 256 + threadIdx.x;
  const int stride = gridDim.x * 256;
  const int total = E + N;
  for (; i < total; i += stride) {
    int r, c;
    if (i < E) {
      if (is64) { r = ei[2 * i]; c = ei[2 * (E + i)]; }
      else      { r = ei[i];     c = ei[E + i]; }
    } else {
      r = i - E; c = r;  // self loop
    }
    int pos = atomicAdd(&cursor[r], 1);
    scol[pos] = c;
  }
}

// ---------------- per-row online softmax + SpMM, one wave per row ----------------
// h is bf16-packed: row stride 64 uints (128 bf16). lane owns elems 2*lane,2*lane+1.
__global__ __launch_bounds__(256) void gat_agg(
    const uint* __restrict__ hb, const float* __restrict__ s, const float* __restrict__ dv,
    const int* __restrict__ offsets, const int* __restrict__ scol,
    float* __restrict__ out, int N)
{
  int wid = (int)((blockIdx.x * 256 + threadIdx.x) >> 6);
  int lane = threadIdx.x & 63;
  if (wid >= N) return;
  const int head = lane >> 3;
  const int beg = offsets[wid];
  const int end = offsets[wid + 1];
  const float sl = s[(size_t)wid * 8 + head];

  // 2-deep software pipeline: scol 2 ahead, gathers 1 ahead
  int c1 = scol[beg];                                  // col for iter i
  int c2 = (beg + 1 < end) ? scol[beg + 1] : c1;       // col for iter i+1
  float dl0 = dv[(size_t)c1 * 8 + head];
  uint  hu0 = hb[(size_t)c1 * 64 + lane];

  float m = -INFINITY, z = 0.f, ax = 0.f, ay = 0.f;
  for (int i = beg; i < end; ++i) {
    int c3 = (i + 2 < end) ? scol[i + 2] : c2;
    float dl1 = dv[(size_t)c2 * 8 + head];
    uint  hu1 = hb[(size_t)c2 * 64 + lane];

    float hx = __uint_as_float(hu0 << 16);
    float hy = __uint_as_float(hu0 & 0xFFFF0000u);
    float e = sl + dl0;
    e = (e > 0.f) ? e : NEG_SLOPE * e;
    float mn = fmaxf(m, e);
    float sc  = __expf(m - mn);   // first iter: exp(-inf) = 0
    float wgt = __expf(e - mn);
    z  = z * sc + wgt;
    ax = ax * sc + wgt * hx;
    ay = ay * sc + wgt * hy;
    m = mn;

    c2 = c3; dl0 = dl1; hu0 = hu1;
  }
  float inv = 1.f / z;
  *(float2*)(out + (size_t)wid * 128 + lane * 2) = make_float2(ax * inv, ay * inv);
}

extern "C" void kernel_launch(void* const* d_in, const int* in_sizes, int n_in,
                              void* d_out, int out_size, void* d_ws, size_t ws_size,
                              hipStream_t stream) {
  const float* x    = (const float*)d_in[0];
  const int*   ei   = (const int*)d_in[1];
  const float* W    = (const float*)d_in[2];
  const float* srcA = (const float*)d_in[3];
  const float* dstA = (const float*)d_in[4];
  float* out = (float*)d_out;
  const int N = in_sizes[0] / 128;
  const int E = in_sizes[1] / 2;

  // workspace layout (wbf right after dv to keep 16B alignment)
  ushort* hbuf = (ushort*)d_ws;                       // N*128 bf16
  float* s  = (float*)(hbuf + (size_t)N * 128);       // N*8
  float* dv = s + (size_t)N * 8;                      // N*8
  ushort* wbf = (ushort*)(dv + (size_t)N * 8);        // 36*64*8 bf16 = 36864 B
  int* count   = (int*)((char*)wbf + 36864);          // N
  int* offsets = count + N;                           // N+1
  int* cursor  = offsets + (N + 1);                   // N
  int* partial = cursor + N;                          // 1024
  int* flag    = partial + 1024;                      // 4 (padded)
  int* scol    = flag + 4;                            // E+N

  const int nchunks = (N + 63) / 64;

  (void)hipMemsetAsync(count, 0, (size_t)N * sizeof(int), stream);
  gat_prep<<<9, 256, 0, stream>>>(W, srcA, dstA, wbf);
  gat_gemm_mfma<<<512, 256, 0, stream>>>(x, wbf, hbuf, s, dv, N, nchunks);
  gat_detect<<<1, 256, 0, stream>>>(ei, E, flag);
  gat_hist<<<2048, 256, 0, stream>>>(ei, E, flag, count);
  const int nb = (N + 1023) / 1024;
  gat_scan_part<<<nb, 256, 0, stream>>>(count, N, partial);
  gat_scan_mid<<<1, 1024, 0, stream>>>(partial, nb);
  gat_scan_final<<<nb, 256, 0, stream>>>(count, N, partial, offsets, cursor, E + N);
  gat_scatter<<<2048, 256, 0, stream>>>(ei, E, N, flag, cursor, scol);
  gat_agg<<<(N + 3) / 4, 256, 0, stream>>>((const uint*)hbuf, s, dv, offsets, scol, out, N);
}

// Round 5
// 259.669 us; speedup vs baseline: 2.0375x; 1.4295x over previous
//
#include <hip/hip_runtime.h>
#include <hip/hip_bf16.h>
#include <math.h>

#define NEG_SLOPE 0.2f

typedef __attribute__((ext_vector_type(8))) short short8v;
typedef __attribute__((ext_vector_type(4))) float f32x4;

// ---------------- prep: pack B fragments [W^T | W^T*Asrc | W^T*Adst] in bf16 ----
__global__ __launch_bounds__(256) void gat_prep(
    const float* __restrict__ W, const float* __restrict__ srcA,
    const float* __restrict__ dstA, ushort* __restrict__ wbf)
{
  int tid = blockIdx.x * 256 + threadIdx.x;  // 0..2303
  if (tid >= 36 * 64) return;
  int frag = tid >> 6, lane = tid & 63;
  int nt = frag >> 2, ks = frag & 3;
  int kbase = ks * 32 + (lane >> 4) * 8;
  ushort v[8];
  if (nt < 8) {
    int r = nt * 16 + (lane & 15);   // output col n -> W row
#pragma unroll
    for (int j = 0; j < 8; ++j)
      v[j] = __bfloat16_as_ushort(__float2bfloat16(W[(size_t)r * 128 + kbase + j]));
  } else {
    int n = lane & 15;
    int hd = n & 7;
    const float* av = (n < 8) ? srcA : dstA;
#pragma unroll
    for (int j = 0; j < 8; ++j) {
      float acc = 0.f;
      int k = kbase + j;
      for (int d = 0; d < 16; ++d)
        acc += W[(size_t)(hd * 16 + d) * 128 + k] * av[hd * 16 + d];
      v[j] = __bfloat16_as_ushort(__float2bfloat16(acc));
    }
  }
  ushort* dst = wbf + ((size_t)frag * 64 + lane) * 8;
#pragma unroll
  for (int j = 0; j < 8; ++j) dst[j] = v[j];
}

// ---------------- MFMA GEMM: [h | s | dv] = x * [W^T | Ps | Pd] ----------------
__global__ __launch_bounds__(256, 2) void gat_gemm_mfma(
    const float* __restrict__ x, const ushort* __restrict__ wbf,
    ushort* __restrict__ hb, float* __restrict__ s, float* __restrict__ dv,
    int N, int nchunks)
{
  const int wave = threadIdx.x >> 6, lane = threadIdx.x & 63;
  const int lrow = lane & 15, lkg = lane >> 4;

  short8v b[36];
  const short8v* wv = (const short8v*)wbf;
#pragma unroll
  for (int f = 0; f < 36; ++f) b[f] = wv[(size_t)f * 64 + lane];

  for (int chunk = blockIdx.x; chunk < nchunks; chunk += gridDim.x) {
    const int r0 = chunk * 64 + wave * 16;
    int arow = r0 + lrow; if (arow > N - 1) arow = N - 1;
    const float* xr = x + (size_t)arow * 128 + lkg * 8;

    f32x4 acc[9];
#pragma unroll
    for (int t = 0; t < 9; ++t) acc[t] = (f32x4){0.f, 0.f, 0.f, 0.f};

#pragma unroll
    for (int ks = 0; ks < 4; ++ks) {
      float4 x0 = *(const float4*)(xr + ks * 32);
      float4 x1 = *(const float4*)(xr + ks * 32 + 4);
      short8v a;
      a[0] = (short)__bfloat16_as_ushort(__float2bfloat16(x0.x));
      a[1] = (short)__bfloat16_as_ushort(__float2bfloat16(x0.y));
      a[2] = (short)__bfloat16_as_ushort(__float2bfloat16(x0.z));
      a[3] = (short)__bfloat16_as_ushort(__float2bfloat16(x0.w));
      a[4] = (short)__bfloat16_as_ushort(__float2bfloat16(x1.x));
      a[5] = (short)__bfloat16_as_ushort(__float2bfloat16(x1.y));
      a[6] = (short)__bfloat16_as_ushort(__float2bfloat16(x1.z));
      a[7] = (short)__bfloat16_as_ushort(__float2bfloat16(x1.w));
#pragma unroll
      for (int t = 0; t < 9; ++t)
        acc[t] = __builtin_amdgcn_mfma_f32_16x16x32_bf16(a, b[t * 4 + ks], acc[t], 0, 0, 0);
    }

    const int rbase = r0 + lkg * 4;  // C/D: row = (lane>>4)*4 + reg, col = lane&15
#pragma unroll
    for (int t = 0; t < 8; ++t) {
#pragma unroll
      for (int r = 0; r < 4; ++r) {
        int row = rbase + r;
        if (row < N)
          hb[(size_t)row * 128 + t * 16 + lrow] =
              __bfloat16_as_ushort(__float2bfloat16(acc[t][r]));
      }
    }
#pragma unroll
    for (int r = 0; r < 4; ++r) {
      int row = rbase + r;
      if (row < N) {
        if (lrow < 8) s[(size_t)row * 8 + lrow] = acc[8][r];
        else          dv[(size_t)row * 8 + (lrow - 8)] = acc[8][r];
      }
    }
  }
}

// ---------------- int64-vs-int32 edge-index detection ----------------
__global__ void gat_detect(const int* __restrict__ ei, int E, int* __restrict__ flag)
{
  __shared__ int any;
  if (threadIdx.x == 0) any = 0;
  __syncthreads();
  int n = E < 512 ? E : 512;
  int local = 0;
  for (int i = threadIdx.x; i < n; i += 256)
    if (ei[2 * i + 1] != 0) local = 1;
  if (local) atomicOr(&any, 1);
  __syncthreads();
  if (threadIdx.x == 0) *flag = (any == 0) ? 1 : 0;  // 1 => int64 layout
}

// ---------------- histogram of destination rows (+ per-edge rank) ----------------
__global__ __launch_bounds__(256) void gat_hist(
    const int* __restrict__ ei, int E, const int* __restrict__ flag,
    int* __restrict__ count, int* __restrict__ rank, int userank)
{
  const int is64 = *flag;
  int i = blockIdx.x * 256 + threadIdx.x;
  const int stride = gridDim.x * 256;
  for (; i < E; i += stride) {
    int r = is64 ? ei[2 * i] : ei[i];
    int old = atomicAdd(&count[r], 1);
    if (userank) rank[i] = old;
  }
}

// ---------------- 2-level exclusive scan of (count[n] + 1) ----------------
__global__ __launch_bounds__(256) void gat_scan_part(
    const int* __restrict__ count, int N, int* __restrict__ partial)
{
  __shared__ int sm[256];
  int base = blockIdx.x * 1024;
  int tsum = 0;
  for (int i = threadIdx.x; i < 1024; i += 256) {
    int idx = base + i;
    if (idx < N) tsum += count[idx] + 1;  // +1 = self loop
  }
  sm[threadIdx.x] = tsum;
  __syncthreads();
  for (int off = 128; off > 0; off >>= 1) {
    if (threadIdx.x < off) sm[threadIdx.x] += sm[threadIdx.x + off];
    __syncthreads();
  }
  if (threadIdx.x == 0) partial[blockIdx.x] = sm[0];
}

__global__ __launch_bounds__(1024) void gat_scan_mid(int* __restrict__ partial, int nb)
{
  __shared__ int sm[1024];
  int t = threadIdx.x;
  int v = (t < nb) ? partial[t] : 0;
  sm[t] = v;
  __syncthreads();
  int acc = v;
  for (int off = 1; off < 1024; off <<= 1) {
    int other = (t >= off) ? sm[t - off] : 0;
    __syncthreads();
    acc += other;
    sm[t] = acc;
    __syncthreads();
  }
  if (t < nb) partial[t] = acc - v;  // exclusive
}

__global__ __launch_bounds__(256) void gat_scan_final(
    const int* __restrict__ count, int N, const int* __restrict__ partial,
    int* __restrict__ offsets, int* __restrict__ cursor, int total)
{
  __shared__ int sm[256];
  int base = blockIdx.x * 1024 + threadIdx.x * 4;
  int v[4];
  int tsum = 0;
#pragma unroll
  for (int j = 0; j < 4; ++j) {
    int idx = base + j;
    v[j] = (idx < N) ? (count[idx] + 1) : 0;
    tsum += v[j];
  }
  sm[threadIdx.x] = tsum;
  __syncthreads();
  int acc = tsum;
  for (int off = 1; off < 256; off <<= 1) {
    int other = (threadIdx.x >= off) ? sm[threadIdx.x - off] : 0;
    __syncthreads();
    acc += other;
    sm[threadIdx.x] = acc;
    __syncthreads();
  }
  int ex = acc - tsum + partial[blockIdx.x];
#pragma unroll
  for (int j = 0; j < 4; ++j) {
    int idx = base + j;
    if (idx < N) { offsets[idx] = ex; cursor[idx] = ex; ex += v[j]; }
  }
  if (blockIdx.x == 0 && threadIdx.x == 0) offsets[N] = total;
}

// ---------------- atomic-free scatter using precomputed ranks ----------------
__global__ __launch_bounds__(256) void gat_scatter_rank(
    const int* __restrict__ ei, int E, int N, const int* __restrict__ flag,
    const int* __restrict__ offsets, const int* __restrict__ count,
    const int* __restrict__ rank, int* __restrict__ scol)
{
  const int is64 = *flag;
  int i = blockIdx.x * 256 + threadIdx.x;
  const int stride = gridDim.x * 256;
  const int total = E + N;
  for (; i < total; i += stride) {
    int pos, c;
    if (i < E) {
      int r;
      if (is64) { r = ei[2 * i]; c = ei[2 * (E + i)]; }
      else      { r = ei[i];     c = ei[E + i]; }
      pos = offsets[r] + rank[i];
    } else {
      int r = i - E; c = r;                 // self loop -> last slot of row
      pos = offsets[r] + count[r];
    }
    scol[pos] = c;
  }
}

// ---------------- fallback: atomic-cursor scatter (if ws too small) ----------
__global__ __launch_bounds__(256) void gat_scatter(
    const int* __restrict__ ei, int E, int N, const int* __restrict__ flag,
    int* __restrict__ cursor, int* __restrict__ scol)
{
  const int is64 = *flag;
  int i = blockIdx.x * 256 + threadIdx.x;
  const int stride = gridDim.x * 256;
  const int total = E + N;
  for (; i < total; i += stride) {
    int r, c;
    if (i < E) {
      if (is64) { r = ei[2 * i]; c = ei[2 * (E + i)]; }
      else      { r = ei[i];     c = ei[E + i]; }
    } else {
      r = i - E; c = r;  // self loop
    }
    int pos = atomicAdd(&cursor[r], 1);
    scol[pos] = c;
  }
}

// ---------------- per-row online softmax + SpMM, one wave per row ----------------
__global__ __launch_bounds__(256) void gat_agg(
    const uint* __restrict__ hb, const float* __restrict__ s, const float* __restrict__ dv,
    const int* __restrict__ offsets, const int* __restrict__ scol,
    float* __restrict__ out, int N)
{
  int wid = (int)((blockIdx.x * 256 + threadIdx.x) >> 6);
  int lane = threadIdx.x & 63;
  if (wid >= N) return;
  const int head = lane >> 3;
  const int beg = offsets[wid];
  const int end = offsets[wid + 1];
  const float sl = s[(size_t)wid * 8 + head];

  // 2-deep software pipeline: scol 2 ahead, gathers 1 ahead
  int c1 = scol[beg];
  int c2 = (beg + 1 < end) ? scol[beg + 1] : c1;
  float dl0 = dv[(size_t)c1 * 8 + head];
  uint  hu0 = hb[(size_t)c1 * 64 + lane];

  float m = -INFINITY, z = 0.f, ax = 0.f, ay = 0.f;
  for (int i = beg; i < end; ++i) {
    int c3 = (i + 2 < end) ? scol[i + 2] : c2;
    float dl1 = dv[(size_t)c2 * 8 + head];
    uint  hu1 = hb[(size_t)c2 * 64 + lane];

    float hx = __uint_as_float(hu0 << 16);
    float hy = __uint_as_float(hu0 & 0xFFFF0000u);
    float e = sl + dl0;
    e = (e > 0.f) ? e : NEG_SLOPE * e;
    float mn = fmaxf(m, e);
    float sc  = __expf(m - mn);   // first iter: exp(-inf) = 0
    float wgt = __expf(e - mn);
    z  = z * sc + wgt;
    ax = ax * sc + wgt * hx;
    ay = ay * sc + wgt * hy;
    m = mn;

    c2 = c3; dl0 = dl1; hu0 = hu1;
  }
  float inv = 1.f / z;
  *(float2*)(out + (size_t)wid * 128 + lane * 2) = make_float2(ax * inv, ay * inv);
}

extern "C" void kernel_launch(void* const* d_in, const int* in_sizes, int n_in,
                              void* d_out, int out_size, void* d_ws, size_t ws_size,
                              hipStream_t stream) {
  const float* x    = (const float*)d_in[0];
  const int*   ei   = (const int*)d_in[1];
  const float* W    = (const float*)d_in[2];
  const float* srcA = (const float*)d_in[3];
  const float* dstA = (const float*)d_in[4];
  float* out = (float*)d_out;
  const int N = in_sizes[0] / 128;
  const int E = in_sizes[1] / 2;

  // workspace layout
  ushort* hbuf = (ushort*)d_ws;                       // N*128 bf16
  float* s  = (float*)(hbuf + (size_t)N * 128);       // N*8
  float* dv = s + (size_t)N * 8;                      // N*8
  ushort* wbf = (ushort*)(dv + (size_t)N * 8);        // 36*64*8 bf16 = 36864 B
  int* count   = (int*)((char*)wbf + 36864);          // N
  int* offsets = count + N;                           // N+1
  int* cursor  = offsets + (N + 1);                   // N
  int* partial = cursor + N;                          // 1024
  int* flag    = partial + 1024;                      // 4 (padded)
  int* scol    = flag + 4;                            // E+N
  int* rank    = scol + (E + N);                      // E (optional)

  const size_t need_rank = (size_t)((char*)(rank + E) - (char*)d_ws);
  const int userank = (ws_size >= need_rank) ? 1 : 0;

  const int nchunks = (N + 63) / 64;

  (void)hipMemsetAsync(count, 0, (size_t)N * sizeof(int), stream);
  gat_prep<<<9, 256, 0, stream>>>(W, srcA, dstA, wbf);
  gat_gemm_mfma<<<512, 256, 0, stream>>>(x, wbf, hbuf, s, dv, N, nchunks);
  gat_detect<<<1, 256, 0, stream>>>(ei, E, flag);
  gat_hist<<<2048, 256, 0, stream>>>(ei, E, flag, count, rank, userank);
  const int nb = (N + 1023) / 1024;
  gat_scan_part<<<nb, 256, 0, stream>>>(count, N, partial);
  gat_scan_mid<<<1, 1024, 0, stream>>>(partial, nb);
  gat_scan_final<<<nb, 256, 0, stream>>>(count, N, partial, offsets, cursor, E + N);
  if (userank)
    gat_scatter_rank<<<2048, 256, 0, stream>>>(ei, E, N, flag, offsets, count, rank, scol);
  else
    gat_scatter<<<2048, 256, 0, stream>>>(ei, E, N, flag, cursor, scol);
  gat_agg<<<(N + 3) / 4, 256, 0, stream>>>((const uint*)hbuf, s, dv, offsets, scol, out, N);
}

// Round 6
// 250.981 us; speedup vs baseline: 2.1080x; 1.0346x over previous
//
#include <hip/hip_runtime.h>
#include <hip/hip_bf16.h>
#include <math.h>

#define NEG_SLOPE 0.2f

typedef __attribute__((ext_vector_type(8))) short short8v;
typedef __attribute__((ext_vector_type(4))) float f32x4;

// ---------------- prep: pack B fragments [W^T | W^T*Asrc | W^T*Adst] in bf16 ----
__global__ __launch_bounds__(256) void gat_prep(
    const float* __restrict__ W, const float* __restrict__ srcA,
    const float* __restrict__ dstA, ushort* __restrict__ wbf)
{
  int tid = blockIdx.x * 256 + threadIdx.x;  // 0..2303
  if (tid >= 36 * 64) return;
  int frag = tid >> 6, lane = tid & 63;
  int nt = frag >> 2, ks = frag & 3;
  int kbase = ks * 32 + (lane >> 4) * 8;
  ushort v[8];
  if (nt < 8) {
    int r = nt * 16 + (lane & 15);   // output col n -> W row
#pragma unroll
    for (int j = 0; j < 8; ++j)
      v[j] = __bfloat16_as_ushort(__float2bfloat16(W[(size_t)r * 128 + kbase + j]));
  } else {
    int n = lane & 15;
    int hd = n & 7;
    const float* av = (n < 8) ? srcA : dstA;
#pragma unroll
    for (int j = 0; j < 8; ++j) {
      float acc = 0.f;
      int k = kbase + j;
      for (int d = 0; d < 16; ++d)
        acc += W[(size_t)(hd * 16 + d) * 128 + k] * av[hd * 16 + d];
      v[j] = __bfloat16_as_ushort(__float2bfloat16(acc));
    }
  }
  ushort* dst = wbf + ((size_t)frag * 64 + lane) * 8;
#pragma unroll
  for (int j = 0; j < 8; ++j) dst[j] = v[j];
}

// ---------------- MFMA GEMM: [h | s | dv] = x * [W^T | Ps | Pd] ----------------
__global__ __launch_bounds__(256, 2) void gat_gemm_mfma(
    const float* __restrict__ x, const ushort* __restrict__ wbf,
    ushort* __restrict__ hb, float* __restrict__ s, float* __restrict__ dv,
    int N, int nchunks)
{
  const int wave = threadIdx.x >> 6, lane = threadIdx.x & 63;
  const int lrow = lane & 15, lkg = lane >> 4;

  short8v b[36];
  const short8v* wv = (const short8v*)wbf;
#pragma unroll
  for (int f = 0; f < 36; ++f) b[f] = wv[(size_t)f * 64 + lane];

  for (int chunk = blockIdx.x; chunk < nchunks; chunk += gridDim.x) {
    const int r0 = chunk * 64 + wave * 16;
    int arow = r0 + lrow; if (arow > N - 1) arow = N - 1;
    const float* xr = x + (size_t)arow * 128 + lkg * 8;

    f32x4 acc[9];
#pragma unroll
    for (int t = 0; t < 9; ++t) acc[t] = (f32x4){0.f, 0.f, 0.f, 0.f};

#pragma unroll
    for (int ks = 0; ks < 4; ++ks) {
      float4 x0 = *(const float4*)(xr + ks * 32);
      float4 x1 = *(const float4*)(xr + ks * 32 + 4);
      short8v a;
      a[0] = (short)__bfloat16_as_ushort(__float2bfloat16(x0.x));
      a[1] = (short)__bfloat16_as_ushort(__float2bfloat16(x0.y));
      a[2] = (short)__bfloat16_as_ushort(__float2bfloat16(x0.z));
      a[3] = (short)__bfloat16_as_ushort(__float2bfloat16(x0.w));
      a[4] = (short)__bfloat16_as_ushort(__float2bfloat16(x1.x));
      a[5] = (short)__bfloat16_as_ushort(__float2bfloat16(x1.y));
      a[6] = (short)__bfloat16_as_ushort(__float2bfloat16(x1.z));
      a[7] = (short)__bfloat16_as_ushort(__float2bfloat16(x1.w));
#pragma unroll
      for (int t = 0; t < 9; ++t)
        acc[t] = __builtin_amdgcn_mfma_f32_16x16x32_bf16(a, b[t * 4 + ks], acc[t], 0, 0, 0);
    }

    const int rbase = r0 + lkg * 4;  // C/D: row = (lane>>4)*4 + reg, col = lane&15
#pragma unroll
    for (int t = 0; t < 8; ++t) {
#pragma unroll
      for (int r = 0; r < 4; ++r) {
        int row = rbase + r;
        if (row < N)
          hb[(size_t)row * 128 + t * 16 + lrow] =
              __bfloat16_as_ushort(__float2bfloat16(acc[t][r]));
      }
    }
#pragma unroll
    for (int r = 0; r < 4; ++r) {
      int row = rbase + r;
      if (row < N) {
        if (lrow < 8) s[(size_t)row * 8 + lrow] = acc[8][r];
        else          dv[(size_t)row * 8 + (lrow - 8)] = acc[8][r];
      }
    }
  }
}

// ---------------- int64-vs-int32 edge-index detection ----------------
__global__ void gat_detect(const int* __restrict__ ei, int E, int* __restrict__ flag)
{
  __shared__ int any;
  if (threadIdx.x == 0) any = 0;
  __syncthreads();
  int n = E < 512 ? E : 512;
  int local = 0;
  for (int i = threadIdx.x; i < n; i += 256)
    if (ei[2 * i + 1] != 0) local = 1;
  if (local) atomicOr(&any, 1);
  __syncthreads();
  if (threadIdx.x == 0) *flag = (any == 0) ? 1 : 0;  // 1 => int64 layout
}

// ---------------- histogram of destination rows (+ per-edge rank) ----------------
__global__ __launch_bounds__(256) void gat_hist(
    const int* __restrict__ ei, int E, const int* __restrict__ flag,
    int* __restrict__ count, int* __restrict__ rank, int userank)
{
  const int is64 = *flag;
  int i = blockIdx.x * 256 + threadIdx.x;
  const int stride = gridDim.x * 256;
  for (; i < E; i += stride) {
    int r = is64 ? ei[2 * i] : ei[i];
    int old = atomicAdd(&count[r], 1);
    if (userank) rank[i] = old;
  }
}

// ---------------- 2-level exclusive scan of (count[n] + 1) ----------------
__global__ __launch_bounds__(256) void gat_scan_part(
    const int* __restrict__ count, int N, int* __restrict__ partial)
{
  __shared__ int sm[256];
  int base = blockIdx.x * 1024;
  int tsum = 0;
  for (int i = threadIdx.x; i < 1024; i += 256) {
    int idx = base + i;
    if (idx < N) tsum += count[idx] + 1;  // +1 = self loop
  }
  sm[threadIdx.x] = tsum;
  __syncthreads();
  for (int off = 128; off > 0; off >>= 1) {
    if (threadIdx.x < off) sm[threadIdx.x] += sm[threadIdx.x + off];
    __syncthreads();
  }
  if (threadIdx.x == 0) partial[blockIdx.x] = sm[0];
}

__global__ __launch_bounds__(1024) void gat_scan_mid(int* __restrict__ partial, int nb)
{
  __shared__ int sm[1024];
  int t = threadIdx.x;
  int v = (t < nb) ? partial[t] : 0;
  sm[t] = v;
  __syncthreads();
  int acc = v;
  for (int off = 1; off < 1024; off <<= 1) {
    int other = (t >= off) ? sm[t - off] : 0;
    __syncthreads();
    acc += other;
    sm[t] = acc;
    __syncthreads();
  }
  if (t < nb) partial[t] = acc - v;  // exclusive
}

__global__ __launch_bounds__(256) void gat_scan_final(
    const int* __restrict__ count, int N, const int* __restrict__ partial,
    int* __restrict__ offsets, int* __restrict__ cursor, int total)
{
  __shared__ int sm[256];
  int base = blockIdx.x * 1024 + threadIdx.x * 4;
  int v[4];
  int tsum = 0;
#pragma unroll
  for (int j = 0; j < 4; ++j) {
    int idx = base + j;
    v[j] = (idx < N) ? (count[idx] + 1) : 0;
    tsum += v[j];
  }
  sm[threadIdx.x] = tsum;
  __syncthreads();
  int acc = tsum;
  for (int off = 1; off < 256; off <<= 1) {
    int other = (threadIdx.x >= off) ? sm[threadIdx.x - off] : 0;
    __syncthreads();
    acc += other;
    sm[threadIdx.x] = acc;
    __syncthreads();
  }
  int ex = acc - tsum + partial[blockIdx.x];
#pragma unroll
  for (int j = 0; j < 4; ++j) {
    int idx = base + j;
    if (idx < N) { offsets[idx] = ex; cursor[idx] = ex; ex += v[j]; }
  }
  if (blockIdx.x == 0 && threadIdx.x == 0) offsets[N] = total;
}

// ---------------- atomic-free scatter using precomputed ranks ----------------
__global__ __launch_bounds__(256) void gat_scatter_rank(
    const int* __restrict__ ei, int E, int N, const int* __restrict__ flag,
    const int* __restrict__ offsets, const int* __restrict__ count,
    const int* __restrict__ rank, int* __restrict__ scol)
{
  const int is64 = *flag;
  int i = blockIdx.x * 256 + threadIdx.x;
  const int stride = gridDim.x * 256;
  const int total = E + N;
  for (; i < total; i += stride) {
    int pos, c;
    if (i < E) {
      int r;
      if (is64) { r = ei[2 * i]; c = ei[2 * (E + i)]; }
      else      { r = ei[i];     c = ei[E + i]; }
      pos = offsets[r] + rank[i];
    } else {
      int r = i - E; c = r;                 // self loop -> last slot of row
      pos = offsets[r] + count[r];
    }
    scol[pos] = c;
  }
}

// ---------------- fallback: atomic-cursor scatter (if ws too small) ----------
__global__ __launch_bounds__(256) void gat_scatter(
    const int* __restrict__ ei, int E, int N, const int* __restrict__ flag,
    int* __restrict__ cursor, int* __restrict__ scol)
{
  const int is64 = *flag;
  int i = blockIdx.x * 256 + threadIdx.x;
  const int stride = gridDim.x * 256;
  const int total = E + N;
  for (; i < total; i += stride) {
    int r, c;
    if (i < E) {
      if (is64) { r = ei[2 * i]; c = ei[2 * (E + i)]; }
      else      { r = ei[i];     c = ei[E + i]; }
    } else {
      r = i - E; c = r;  // self loop
    }
    int pos = atomicAdd(&cursor[r], 1);
    scol[pos] = c;
  }
}

// ---------------- per-row softmax + SpMM, one wave per row ----------------
// No online max: logits are leaky_relu(s+d) with |.| <~ 10 for normal data;
// exp() in f32 is safe to ~87. Shortens the carried chain to a single add.
__global__ __launch_bounds__(256) void gat_agg(
    const uint* __restrict__ hb, const float* __restrict__ s, const float* __restrict__ dv,
    const int* __restrict__ offsets, const int* __restrict__ scol,
    float* __restrict__ out, int N)
{
  int wid = (int)((blockIdx.x * 256 + threadIdx.x) >> 6);
  int lane = threadIdx.x & 63;
  if (wid >= N) return;
  const int head = lane >> 3;
  // beg/end are wave-uniform: force to SGPRs so loop control + scol prefetch
  // ride the scalar pipe instead of VALU.
  const int beg = __builtin_amdgcn_readfirstlane(offsets[wid]);
  const int end = __builtin_amdgcn_readfirstlane(offsets[wid + 1]);  // end-1 >= beg (self loop)
  const float sl = s[wid * 8 + head];

  const char* hbp = (const char*)hb;
  const char* dvp = (const char*)dv;
  const uint hoff = (uint)lane * 4u;
  const uint doff = (uint)head * 4u;

  int c1 = scol[beg];
  int i1 = (beg + 1 < end) ? (beg + 1) : (end - 1);
  int c2 = scol[i1];
  float dl0 = *(const float*)(dvp + ((uint)c1 * 32u + doff));
  uint  hu0 = *(const uint*)(hbp + ((uint)c1 * 256u + hoff));

  float z = 0.f, ax = 0.f, ay = 0.f;
  for (int i = beg; i < end; ++i) {
    int i2 = (i + 2 < end) ? (i + 2) : (end - 1);
    int c3 = scol[i2];
    float dl1 = *(const float*)(dvp + ((uint)c2 * 32u + doff));
    uint  hu1 = *(const uint*)(hbp + ((uint)c2 * 256u + hoff));

    float hx = __uint_as_float(hu0 << 16);
    float hy = __uint_as_float(hu0 & 0xFFFF0000u);
    float e = sl + dl0;
    e = fmaxf(e, NEG_SLOPE * e);   // leaky relu
    float w = __expf(e);
    z += w;
    ax = fmaf(w, hx, ax);
    ay = fmaf(w, hy, ay);

    c2 = c3; dl0 = dl1; hu0 = hu1;
  }
  float inv = 1.f / z;
  *(float2*)(out + (size_t)wid * 128 + lane * 2) = make_float2(ax * inv, ay * inv);
}

extern "C" void kernel_launch(void* const* d_in, const int* in_sizes, int n_in,
                              void* d_out, int out_size, void* d_ws, size_t ws_size,
                              hipStream_t stream) {
  const float* x    = (const float*)d_in[0];
  const int*   ei   = (const int*)d_in[1];
  const float* W    = (const float*)d_in[2];
  const float* srcA = (const float*)d_in[3];
  const float* dstA = (const float*)d_in[4];
  float* out = (float*)d_out;
  const int N = in_sizes[0] / 128;
  const int E = in_sizes[1] / 2;

  // workspace layout
  ushort* hbuf = (ushort*)d_ws;                       // N*128 bf16
  float* s  = (float*)(hbuf + (size_t)N * 128);       // N*8
  float* dv = s + (size_t)N * 8;                      // N*8
  ushort* wbf = (ushort*)(dv + (size_t)N * 8);        // 36*64*8 bf16 = 36864 B
  int* count   = (int*)((char*)wbf + 36864);          // N
  int* offsets = count + N;                           // N+1
  int* cursor  = offsets + (N + 1);                   // N
  int* partial = cursor + N;                          // 1024
  int* flag    = partial + 1024;                      // 4 (padded)
  int* scol    = flag + 4;                            // E+N
  int* rank    = scol + (E + N);                      // E (optional)

  const size_t need_rank = (size_t)((char*)(rank + E) - (char*)d_ws);
  const int userank = (ws_size >= need_rank) ? 1 : 0;

  const int nchunks = (N + 63) / 64;

  (void)hipMemsetAsync(count, 0, (size_t)N * sizeof(int), stream);
  gat_prep<<<9, 256, 0, stream>>>(W, srcA, dstA, wbf);
  gat_gemm_mfma<<<512, 256, 0, stream>>>(x, wbf, hbuf, s, dv, N, nchunks);
  gat_detect<<<1, 256, 0, stream>>>(ei, E, flag);
  gat_hist<<<2048, 256, 0, stream>>>(ei, E, flag, count, rank, userank);
  const int nb = (N + 1023) / 1024;
  gat_scan_part<<<nb, 256, 0, stream>>>(count, N, partial);
  gat_scan_mid<<<1, 1024, 0, stream>>>(partial, nb);
  gat_scan_final<<<nb, 256, 0, stream>>>(count, N, partial, offsets, cursor, E + N);
  if (userank)
    gat_scatter_rank<<<2048, 256, 0, stream>>>(ei, E, N, flag, offsets, count, rank, scol);
  else
    gat_scatter<<<2048, 256, 0, stream>>>(ei, E, N, flag, cursor, scol);
  gat_agg<<<(N + 3) / 4, 256, 0, stream>>>((const uint*)hbuf, s, dv, offsets, scol, out, N);
}

// Round 7
// 250.032 us; speedup vs baseline: 2.1160x; 1.0038x over previous
//
#include <hip/hip_runtime.h>
#include <hip/hip_bf16.h>
#include <math.h>

#define NEG_SLOPE 0.2f

typedef __attribute__((ext_vector_type(8))) short short8v;
typedef __attribute__((ext_vector_type(4))) float f32x4;

// ---------------- prep: pack B fragments [W^T | W^T*Asrc | W^T*Adst] in bf16 ----
__global__ __launch_bounds__(256) void gat_prep(
    const float* __restrict__ W, const float* __restrict__ srcA,
    const float* __restrict__ dstA, ushort* __restrict__ wbf)
{
  int tid = blockIdx.x * 256 + threadIdx.x;  // 0..2303
  if (tid >= 36 * 64) return;
  int frag = tid >> 6, lane = tid & 63;
  int nt = frag >> 2, ks = frag & 3;
  int kbase = ks * 32 + (lane >> 4) * 8;
  ushort v[8];
  if (nt < 8) {
    int r = nt * 16 + (lane & 15);   // output col n -> W row
#pragma unroll
    for (int j = 0; j < 8; ++j)
      v[j] = __bfloat16_as_ushort(__float2bfloat16(W[(size_t)r * 128 + kbase + j]));
  } else {
    int n = lane & 15;
    int hd = n & 7;
    const float* av = (n < 8) ? srcA : dstA;
#pragma unroll
    for (int j = 0; j < 8; ++j) {
      float acc = 0.f;
      int k = kbase + j;
      for (int d = 0; d < 16; ++d)
        acc += W[(size_t)(hd * 16 + d) * 128 + k] * av[hd * 16 + d];
      v[j] = __bfloat16_as_ushort(__float2bfloat16(acc));
    }
  }
  ushort* dst = wbf + ((size_t)frag * 64 + lane) * 8;
#pragma unroll
  for (int j = 0; j < 8; ++j) dst[j] = v[j];
}

// ---------------- MFMA GEMM: [h | s | dv] = x * [W^T | Ps | Pd] ----------------
__global__ __launch_bounds__(256, 2) void gat_gemm_mfma(
    const float* __restrict__ x, const ushort* __restrict__ wbf,
    ushort* __restrict__ hb, float* __restrict__ s, float* __restrict__ dv,
    int N, int nchunks)
{
  const int wave = threadIdx.x >> 6, lane = threadIdx.x & 63;
  const int lrow = lane & 15, lkg = lane >> 4;

  short8v b[36];
  const short8v* wv = (const short8v*)wbf;
#pragma unroll
  for (int f = 0; f < 36; ++f) b[f] = wv[(size_t)f * 64 + lane];

  for (int chunk = blockIdx.x; chunk < nchunks; chunk += gridDim.x) {
    const int r0 = chunk * 64 + wave * 16;
    int arow = r0 + lrow; if (arow > N - 1) arow = N - 1;
    const float* xr = x + (size_t)arow * 128 + lkg * 8;

    f32x4 acc[9];
#pragma unroll
    for (int t = 0; t < 9; ++t) acc[t] = (f32x4){0.f, 0.f, 0.f, 0.f};

#pragma unroll
    for (int ks = 0; ks < 4; ++ks) {
      float4 x0 = *(const float4*)(xr + ks * 32);
      float4 x1 = *(const float4*)(xr + ks * 32 + 4);
      short8v a;
      a[0] = (short)__bfloat16_as_ushort(__float2bfloat16(x0.x));
      a[1] = (short)__bfloat16_as_ushort(__float2bfloat16(x0.y));
      a[2] = (short)__bfloat16_as_ushort(__float2bfloat16(x0.z));
      a[3] = (short)__bfloat16_as_ushort(__float2bfloat16(x0.w));
      a[4] = (short)__bfloat16_as_ushort(__float2bfloat16(x1.x));
      a[5] = (short)__bfloat16_as_ushort(__float2bfloat16(x1.y));
      a[6] = (short)__bfloat16_as_ushort(__float2bfloat16(x1.z));
      a[7] = (short)__bfloat16_as_ushort(__float2bfloat16(x1.w));
#pragma unroll
      for (int t = 0; t < 9; ++t)
        acc[t] = __builtin_amdgcn_mfma_f32_16x16x32_bf16(a, b[t * 4 + ks], acc[t], 0, 0, 0);
    }

    const int rbase = r0 + lkg * 4;  // C/D: row = (lane>>4)*4 + reg, col = lane&15
#pragma unroll
    for (int t = 0; t < 8; ++t) {
#pragma unroll
      for (int r = 0; r < 4; ++r) {
        int row = rbase + r;
        if (row < N)
          hb[(size_t)row * 128 + t * 16 + lrow] =
              __bfloat16_as_ushort(__float2bfloat16(acc[t][r]));
      }
    }
#pragma unroll
    for (int r = 0; r < 4; ++r) {
      int row = rbase + r;
      if (row < N) {
        if (lrow < 8) s[(size_t)row * 8 + lrow] = acc[8][r];
        else          dv[(size_t)row * 8 + (lrow - 8)] = acc[8][r];
      }
    }
  }
}

// ---------------- int64-vs-int32 edge-index detection ----------------
__global__ void gat_detect(const int* __restrict__ ei, int E, int* __restrict__ flag)
{
  __shared__ int any;
  if (threadIdx.x == 0) any = 0;
  __syncthreads();
  int n = E < 512 ? E : 512;
  int local = 0;
  for (int i = threadIdx.x; i < n; i += 256)
    if (ei[2 * i + 1] != 0) local = 1;
  if (local) atomicOr(&any, 1);
  __syncthreads();
  if (threadIdx.x == 0) *flag = (any == 0) ? 1 : 0;  // 1 => int64 layout
}

// ---------------- histogram of destination rows (+ per-edge rank) ----------------
__global__ __launch_bounds__(256) void gat_hist(
    const int* __restrict__ ei, int E, const int* __restrict__ flag,
    int* __restrict__ count, int* __restrict__ rank, int userank)
{
  const int is64 = *flag;
  int i = blockIdx.x * 256 + threadIdx.x;
  const int stride = gridDim.x * 256;
  for (; i < E; i += stride) {
    int r = is64 ? ei[2 * i] : ei[i];
    int old = atomicAdd(&count[r], 1);
    if (userank) rank[i] = old;
  }
}

// ---------------- 2-level exclusive scan of (count[n] + 1) ----------------
__global__ __launch_bounds__(256) void gat_scan_part(
    const int* __restrict__ count, int N, int* __restrict__ partial)
{
  __shared__ int sm[256];
  int base = blockIdx.x * 1024;
  int tsum = 0;
  for (int i = threadIdx.x; i < 1024; i += 256) {
    int idx = base + i;
    if (idx < N) tsum += count[idx] + 1;  // +1 = self loop
  }
  sm[threadIdx.x] = tsum;
  __syncthreads();
  for (int off = 128; off > 0; off >>= 1) {
    if (threadIdx.x < off) sm[threadIdx.x] += sm[threadIdx.x + off];
    __syncthreads();
  }
  if (threadIdx.x == 0) partial[blockIdx.x] = sm[0];
}

__global__ __launch_bounds__(1024) void gat_scan_mid(int* __restrict__ partial, int nb)
{
  __shared__ int sm[1024];
  int t = threadIdx.x;
  int v = (t < nb) ? partial[t] : 0;
  sm[t] = v;
  __syncthreads();
  int acc = v;
  for (int off = 1; off < 1024; off <<= 1) {
    int other = (t >= off) ? sm[t - off] : 0;
    __syncthreads();
    acc += other;
    sm[t] = acc;
    __syncthreads();
  }
  if (t < nb) partial[t] = acc - v;  // exclusive
}

__global__ __launch_bounds__(256) void gat_scan_final(
    const int* __restrict__ count, int N, const int* __restrict__ partial,
    int* __restrict__ offsets, int* __restrict__ cursor, int total)
{
  __shared__ int sm[256];
  int base = blockIdx.x * 1024 + threadIdx.x * 4;
  int v[4];
  int tsum = 0;
#pragma unroll
  for (int j = 0; j < 4; ++j) {
    int idx = base + j;
    v[j] = (idx < N) ? (count[idx] + 1) : 0;
    tsum += v[j];
  }
  sm[threadIdx.x] = tsum;
  __syncthreads();
  int acc = tsum;
  for (int off = 1; off < 256; off <<= 1) {
    int other = (threadIdx.x >= off) ? sm[threadIdx.x - off] : 0;
    __syncthreads();
    acc += other;
    sm[threadIdx.x] = acc;
    __syncthreads();
  }
  int ex = acc - tsum + partial[blockIdx.x];
#pragma unroll
  for (int j = 0; j < 4; ++j) {
    int idx = base + j;
    if (idx < N) { offsets[idx] = ex; cursor[idx] = ex; ex += v[j]; }
  }
  if (blockIdx.x == 0 && threadIdx.x == 0) offsets[N] = total;
}

// ---------------- atomic-free scatter using precomputed ranks ----------------
__global__ __launch_bounds__(256) void gat_scatter_rank(
    const int* __restrict__ ei, int E, int N, const int* __restrict__ flag,
    const int* __restrict__ offsets, const int* __restrict__ count,
    const int* __restrict__ rank, int* __restrict__ scol)
{
  const int is64 = *flag;
  int i = blockIdx.x * 256 + threadIdx.x;
  const int stride = gridDim.x * 256;
  const int total = E + N;
  for (; i < total; i += stride) {
    int pos, c;
    if (i < E) {
      int r;
      if (is64) { r = ei[2 * i]; c = ei[2 * (E + i)]; }
      else      { r = ei[i];     c = ei[E + i]; }
      pos = offsets[r] + rank[i];
    } else {
      int r = i - E; c = r;                 // self loop -> last slot of row
      pos = offsets[r] + count[r];
    }
    scol[pos] = c;
  }
}

// ---------------- fallback: atomic-cursor scatter (if ws too small) ----------
__global__ __launch_bounds__(256) void gat_scatter(
    const int* __restrict__ ei, int E, int N, const int* __restrict__ flag,
    int* __restrict__ cursor, int* __restrict__ scol)
{
  const int is64 = *flag;
  int i = blockIdx.x * 256 + threadIdx.x;
  const int stride = gridDim.x * 256;
  const int total = E + N;
  for (; i < total; i += stride) {
    int r, c;
    if (i < E) {
      if (is64) { r = ei[2 * i]; c = ei[2 * (E + i)]; }
      else      { r = ei[i];     c = ei[E + i]; }
    } else {
      r = i - E; c = r;  // self loop
    }
    int pos = atomicAdd(&cursor[r], 1);
    scol[pos] = c;
  }
}

// ---------------- per-row softmax + SpMM, one wave per row ----------------
// No online max (logits bounded for normal data). Depth-3 software pipeline:
// 3 x {scol, dv, h-row} loads in flight per wave to cover gather latency.
__global__ __launch_bounds__(256) void gat_agg(
    const uint* __restrict__ hb, const float* __restrict__ s, const float* __restrict__ dv,
    const int* __restrict__ offsets, const int* __restrict__ scol,
    float* __restrict__ out, int N)
{
  int wid = (int)((blockIdx.x * 256 + threadIdx.x) >> 6);
  int lane = threadIdx.x & 63;
  if (wid >= N) return;
  const int head = lane >> 3;
  const int beg = __builtin_amdgcn_readfirstlane(offsets[wid]);
  const int end = __builtin_amdgcn_readfirstlane(offsets[wid + 1]);
  const int last = end - 1;                 // end-1 >= beg (self loop guarantees >=1)
  const float sl = s[wid * 8 + head];

  const char* hbp = (const char*)hb;
  const char* dvp = (const char*)dv;
  const uint hoff = (uint)lane * 4u;
  const uint doff = (uint)head * 4u;

  // preload slots a (i), b (i+1), c (i+2); clamped to last
  int ib = (beg + 1 < last) ? beg + 1 : last;
  int ic = (beg + 2 < last) ? beg + 2 : last;
  int ca = scol[beg], cb = scol[ib], cc = scol[ic];
  float dla = *(const float*)(dvp + ((uint)ca * 32u + doff));
  uint  hua = *(const uint*)(hbp + ((uint)ca * 256u + hoff));
  float dlb = *(const float*)(dvp + ((uint)cb * 32u + doff));
  uint  hub = *(const uint*)(hbp + ((uint)cb * 256u + hoff));
  float dlc = *(const float*)(dvp + ((uint)cc * 32u + doff));
  uint  huc = *(const uint*)(hbp + ((uint)cc * 256u + hoff));

  float z = 0.f, ax = 0.f, ay = 0.f;
  for (int i = beg; i < end; ++i) {
    // issue loads for slot i+3
    int i3 = (i + 3 < last) ? i + 3 : last;
    int cn = scol[i3];
    float dln = *(const float*)(dvp + ((uint)cn * 32u + doff));
    uint  hun = *(const uint*)(hbp + ((uint)cn * 256u + hoff));

    // consume slot a
    float hx = __uint_as_float(hua << 16);
    float hy = __uint_as_float(hua & 0xFFFF0000u);
    float e = sl + dla;
    e = fmaxf(e, NEG_SLOPE * e);   // leaky relu
    float w = __expf(e);
    z += w;
    ax = fmaf(w, hx, ax);
    ay = fmaf(w, hy, ay);

    // rotate slots
    hua = hub; dla = dlb;
    hub = huc; dlb = dlc;
    huc = hun; dlc = dln;
  }
  float inv = 1.f / z;
  *(float2*)(out + (size_t)wid * 128 + lane * 2) = make_float2(ax * inv, ay * inv);
}

extern "C" void kernel_launch(void* const* d_in, const int* in_sizes, int n_in,
                              void* d_out, int out_size, void* d_ws, size_t ws_size,
                              hipStream_t stream) {
  const float* x    = (const float*)d_in[0];
  const int*   ei   = (const int*)d_in[1];
  const float* W    = (const float*)d_in[2];
  const float* srcA = (const float*)d_in[3];
  const float* dstA = (const float*)d_in[4];
  float* out = (float*)d_out;
  const int N = in_sizes[0] / 128;
  const int E = in_sizes[1] / 2;

  // workspace layout
  ushort* hbuf = (ushort*)d_ws;                       // N*128 bf16
  float* s  = (float*)(hbuf + (size_t)N * 128);       // N*8
  float* dv = s + (size_t)N * 8;                      // N*8
  ushort* wbf = (ushort*)(dv + (size_t)N * 8);        // 36*64*8 bf16 = 36864 B
  int* count   = (int*)((char*)wbf + 36864);          // N
  int* offsets = count + N;                           // N+1
  int* cursor  = offsets + (N + 1);                   // N
  int* partial = cursor + N;                          // 1024
  int* flag    = partial + 1024;                      // 4 (padded)
  int* scol    = flag + 4;                            // E+N
  int* rank    = scol + (E + N);                      // E (optional)

  const size_t need_rank = (size_t)((char*)(rank + E) - (char*)d_ws);
  const int userank = (ws_size >= need_rank) ? 1 : 0;

  const int nchunks = (N + 63) / 64;

  (void)hipMemsetAsync(count, 0, (size_t)N * sizeof(int), stream);
  gat_prep<<<9, 256, 0, stream>>>(W, srcA, dstA, wbf);
  gat_gemm_mfma<<<512, 256, 0, stream>>>(x, wbf, hbuf, s, dv, N, nchunks);
  gat_detect<<<1, 256, 0, stream>>>(ei, E, flag);
  gat_hist<<<2048, 256, 0, stream>>>(ei, E, flag, count, rank, userank);
  const int nb = (N + 1023) / 1024;
  gat_scan_part<<<nb, 256, 0, stream>>>(count, N, partial);
  gat_scan_mid<<<1, 1024, 0, stream>>>(partial, nb);
  gat_scan_final<<<nb, 256, 0, stream>>>(count, N, partial, offsets, cursor, E + N);
  if (userank)
    gat_scatter_rank<<<2048, 256, 0, stream>>>(ei, E, N, flag, offsets, count, rank, scol);
  else
    gat_scatter<<<2048, 256, 0, stream>>>(ei, E, N, flag, cursor, scol);
  gat_agg<<<(N + 3) / 4, 256, 0, stream>>>((const uint*)hbuf, s, dv, offsets, scol, out, N);
}

// Round 8
// 216.128 us; speedup vs baseline: 2.4479x; 1.1569x over previous
//
#include <hip/hip_runtime.h>
#include <hip/hip_bf16.h>
#include <math.h>

#define NEG_SLOPE 0.2f

typedef __attribute__((ext_vector_type(8))) short short8v;
typedef __attribute__((ext_vector_type(4))) float f32x4;

// ---------------- prep: pack B fragments [W^T | W^T*Asrc | W^T*Adst] in bf16 ----
__global__ __launch_bounds__(256) void gat_prep(
    const float* __restrict__ W, const float* __restrict__ srcA,
    const float* __restrict__ dstA, ushort* __restrict__ wbf)
{
  int tid = blockIdx.x * 256 + threadIdx.x;  // 0..2303
  if (tid >= 36 * 64) return;
  int frag = tid >> 6, lane = tid & 63;
  int nt = frag >> 2, ks = frag & 3;
  int kbase = ks * 32 + (lane >> 4) * 8;
  ushort v[8];
  if (nt < 8) {
    int r = nt * 16 + (lane & 15);   // output col n -> W row
#pragma unroll
    for (int j = 0; j < 8; ++j)
      v[j] = __bfloat16_as_ushort(__float2bfloat16(W[(size_t)r * 128 + kbase + j]));
  } else {
    int n = lane & 15;
    int hd = n & 7;
    const float* av = (n < 8) ? srcA : dstA;
#pragma unroll
    for (int j = 0; j < 8; ++j) {
      float acc = 0.f;
      int k = kbase + j;
      for (int d = 0; d < 16; ++d)
        acc += W[(size_t)(hd * 16 + d) * 128 + k] * av[hd * 16 + d];
      v[j] = __bfloat16_as_ushort(__float2bfloat16(acc));
    }
  }
  ushort* dst = wbf + ((size_t)frag * 64 + lane) * 8;
#pragma unroll
  for (int j = 0; j < 8; ++j) dst[j] = v[j];
}

// ---------------- MFMA GEMM: [h | s | dv] = x * [W^T | Ps | Pd] ----------------
__global__ __launch_bounds__(256, 2) void gat_gemm_mfma(
    const float* __restrict__ x, const ushort* __restrict__ wbf,
    ushort* __restrict__ hb, float* __restrict__ s, float* __restrict__ dv,
    int N, int nchunks)
{
  const int wave = threadIdx.x >> 6, lane = threadIdx.x & 63;
  const int lrow = lane & 15, lkg = lane >> 4;

  short8v b[36];
  const short8v* wv = (const short8v*)wbf;
#pragma unroll
  for (int f = 0; f < 36; ++f) b[f] = wv[(size_t)f * 64 + lane];

  for (int chunk = blockIdx.x; chunk < nchunks; chunk += gridDim.x) {
    const int r0 = chunk * 64 + wave * 16;
    int arow = r0 + lrow; if (arow > N - 1) arow = N - 1;
    const float* xr = x + (size_t)arow * 128 + lkg * 8;

    f32x4 acc[9];
#pragma unroll
    for (int t = 0; t < 9; ++t) acc[t] = (f32x4){0.f, 0.f, 0.f, 0.f};

#pragma unroll
    for (int ks = 0; ks < 4; ++ks) {
      float4 x0 = *(const float4*)(xr + ks * 32);
      float4 x1 = *(const float4*)(xr + ks * 32 + 4);
      short8v a;
      a[0] = (short)__bfloat16_as_ushort(__float2bfloat16(x0.x));
      a[1] = (short)__bfloat16_as_ushort(__float2bfloat16(x0.y));
      a[2] = (short)__bfloat16_as_ushort(__float2bfloat16(x0.z));
      a[3] = (short)__bfloat16_as_ushort(__float2bfloat16(x0.w));
      a[4] = (short)__bfloat16_as_ushort(__float2bfloat16(x1.x));
      a[5] = (short)__bfloat16_as_ushort(__float2bfloat16(x1.y));
      a[6] = (short)__bfloat16_as_ushort(__float2bfloat16(x1.z));
      a[7] = (short)__bfloat16_as_ushort(__float2bfloat16(x1.w));
#pragma unroll
      for (int t = 0; t < 9; ++t)
        acc[t] = __builtin_amdgcn_mfma_f32_16x16x32_bf16(a, b[t * 4 + ks], acc[t], 0, 0, 0);
    }

    const int rbase = r0 + lkg * 4;  // C/D: row = (lane>>4)*4 + reg, col = lane&15
#pragma unroll
    for (int t = 0; t < 8; ++t) {
#pragma unroll
      for (int r = 0; r < 4; ++r) {
        int row = rbase + r;
        if (row < N)
          hb[(size_t)row * 128 + t * 16 + lrow] =
              __bfloat16_as_ushort(__float2bfloat16(acc[t][r]));
      }
    }
#pragma unroll
    for (int r = 0; r < 4; ++r) {
      int row = rbase + r;
      if (row < N) {
        if (lrow < 8) s[(size_t)row * 8 + lrow] = acc[8][r];
        else          dv[(size_t)row * 8 + (lrow - 8)] = acc[8][r];
      }
    }
  }
}

// ---------------- int64-vs-int32 edge-index detection ----------------
__global__ void gat_detect(const int* __restrict__ ei, int E, int* __restrict__ flag)
{
  __shared__ int any;
  if (threadIdx.x == 0) any = 0;
  __syncthreads();
  int n = E < 512 ? E : 512;
  int local = 0;
  for (int i = threadIdx.x; i < n; i += 256)
    if (ei[2 * i + 1] != 0) local = 1;
  if (local) atomicOr(&any, 1);
  __syncthreads();
  if (threadIdx.x == 0) *flag = (any == 0) ? 1 : 0;  // 1 => int64 layout
}

// ---------------- histogram of destination rows (+ per-edge rank) ----------------
__global__ __launch_bounds__(256) void gat_hist(
    const int* __restrict__ ei, int E, const int* __restrict__ flag,
    int* __restrict__ count, int* __restrict__ rank, int userank)
{
  const int is64 = *flag;
  int i = blockIdx.x * 256 + threadIdx.x;
  const int stride = gridDim.x * 256;
  for (; i < E; i += stride) {
    int r = is64 ? ei[2 * i] : ei[i];
    int old = atomicAdd(&count[r], 1);
    if (userank) rank[i] = old;
  }
}

// ---------------- 2-level exclusive scan of (count[n] + 1) ----------------
__global__ __launch_bounds__(256) void gat_scan_part(
    const int* __restrict__ count, int N, int* __restrict__ partial)
{
  __shared__ int sm[256];
  int base = blockIdx.x * 1024;
  int tsum = 0;
  for (int i = threadIdx.x; i < 1024; i += 256) {
    int idx = base + i;
    if (idx < N) tsum += count[idx] + 1;  // +1 = self loop
  }
  sm[threadIdx.x] = tsum;
  __syncthreads();
  for (int off = 128; off > 0; off >>= 1) {
    if (threadIdx.x < off) sm[threadIdx.x] += sm[threadIdx.x + off];
    __syncthreads();
  }
  if (threadIdx.x == 0) partial[blockIdx.x] = sm[0];
}

__global__ __launch_bounds__(1024) void gat_scan_mid(int* __restrict__ partial, int nb)
{
  __shared__ int sm[1024];
  int t = threadIdx.x;
  int v = (t < nb) ? partial[t] : 0;
  sm[t] = v;
  __syncthreads();
  int acc = v;
  for (int off = 1; off < 1024; off <<= 1) {
    int other = (t >= off) ? sm[t - off] : 0;
    __syncthreads();
    acc += other;
    sm[t] = acc;
    __syncthreads();
  }
  if (t < nb) partial[t] = acc - v;  // exclusive
}

__global__ __launch_bounds__(256) void gat_scan_final(
    const int* __restrict__ count, int N, const int* __restrict__ partial,
    int* __restrict__ offsets, int* __restrict__ cursor, int total)
{
  __shared__ int sm[256];
  int base = blockIdx.x * 1024 + threadIdx.x * 4;
  int v[4];
  int tsum = 0;
#pragma unroll
  for (int j = 0; j < 4; ++j) {
    int idx = base + j;
    v[j] = (idx < N) ? (count[idx] + 1) : 0;
    tsum += v[j];
  }
  sm[threadIdx.x] = tsum;
  __syncthreads();
  int acc = tsum;
  for (int off = 1; off < 256; off <<= 1) {
    int other = (threadIdx.x >= off) ? sm[threadIdx.x - off] : 0;
    __syncthreads();
    acc += other;
    sm[threadIdx.x] = acc;
    __syncthreads();
  }
  int ex = acc - tsum + partial[blockIdx.x];
#pragma unroll
  for (int j = 0; j < 4; ++j) {
    int idx = base + j;
    if (idx < N) { offsets[idx] = ex; cursor[idx] = ex; ex += v[j]; }
  }
  if (blockIdx.x == 0 && threadIdx.x == 0) offsets[N] = total;
}

// ---------------- atomic-free scatter using precomputed ranks ----------------
__global__ __launch_bounds__(256) void gat_scatter_rank(
    const int* __restrict__ ei, int E, int N, const int* __restrict__ flag,
    const int* __restrict__ offsets, const int* __restrict__ count,
    const int* __restrict__ rank, int* __restrict__ scol)
{
  const int is64 = *flag;
  int i = blockIdx.x * 256 + threadIdx.x;
  const int stride = gridDim.x * 256;
  const int total = E + N;
  for (; i < total; i += stride) {
    int pos, c;
    if (i < E) {
      int r;
      if (is64) { r = ei[2 * i]; c = ei[2 * (E + i)]; }
      else      { r = ei[i];     c = ei[E + i]; }
      pos = offsets[r] + rank[i];
    } else {
      int r = i - E; c = r;                 // self loop -> last slot of row
      pos = offsets[r] + count[r];
    }
    scol[pos] = c;
  }
}

// ---------------- fallback: atomic-cursor scatter (if ws too small) ----------
__global__ __launch_bounds__(256) void gat_scatter(
    const int* __restrict__ ei, int E, int N, const int* __restrict__ flag,
    int* __restrict__ cursor, int* __restrict__ scol)
{
  const int is64 = *flag;
  int i = blockIdx.x * 256 + threadIdx.x;
  const int stride = gridDim.x * 256;
  const int total = E + N;
  for (; i < total; i += stride) {
    int r, c;
    if (i < E) {
      if (is64) { r = ei[2 * i]; c = ei[2 * (E + i)]; }
      else      { r = ei[i];     c = ei[E + i]; }
    } else {
      r = i - E; c = r;  // self loop
    }
    int pos = atomicAdd(&cursor[r], 1);
    scol[pos] = c;
  }
}

// ---------------- per-row softmax + SpMM, one wave per row ----------------
// scol for the whole row is fetched wave-wide (64 indices per load) and
// broadcast via readlane -> the per-edge address chain has no load in it.
// h/dv gathers run in 8-edge batches, double-buffered (issue B, consume A).
#define GAT_LOAD8(DL, HU, J0)                                        \
  {                                                                  \
    _Pragma("unroll")                                                \
    for (int k = 0; k < 8; ++k) {                                    \
      int c = __builtin_amdgcn_readlane(cvec, (J0) + k);             \
      DL[k] = *(const float*)(dvp + ((uint)c * 32u + doff));         \
      HU[k] = *(const uint*)(hbp + ((uint)c * 256u + hoff));         \
    }                                                                \
  }

#define GAT_CONS8(DL, HU, J0)                                        \
  {                                                                  \
    _Pragma("unroll")                                                \
    for (int k = 0; k < 8; ++k) {                                    \
      float hx = __uint_as_float(HU[k] << 16);                       \
      float hy = __uint_as_float(HU[k] & 0xFFFF0000u);               \
      float e = sl + DL[k];                                          \
      e = fmaxf(e, NEG_SLOPE * e);                                   \
      float w = ((J0) + k < nb) ? __expf(e) : 0.f;                   \
      z += w;                                                        \
      ax = fmaf(w, hx, ax);                                          \
      ay = fmaf(w, hy, ay);                                          \
    }                                                                \
  }

__global__ __launch_bounds__(256) void gat_agg(
    const uint* __restrict__ hb, const float* __restrict__ s, const float* __restrict__ dv,
    const int* __restrict__ offsets, const int* __restrict__ scol,
    float* __restrict__ out, int N)
{
  int wid = (int)((blockIdx.x * 256 + threadIdx.x) >> 6);
  int lane = threadIdx.x & 63;
  if (wid >= N) return;
  const int head = lane >> 3;
  const int beg = __builtin_amdgcn_readfirstlane(offsets[wid]);
  const int end = __builtin_amdgcn_readfirstlane(offsets[wid + 1]);  // >= beg+1 (self loop)
  const float sl = s[wid * 8 + head];

  const char* hbp = (const char*)hb;
  const char* dvp = (const char*)dv;
  const uint hoff = (uint)lane * 4u;
  const uint doff = (uint)head * 4u;

  float z = 0.f, ax = 0.f, ay = 0.f;

  for (int base = beg; base < end; base += 64) {
    const int rem = end - base;                    // scalar
    const int nb = rem < 64 ? rem : 64;            // scalar
    int li = base + (lane < nb ? lane : nb - 1);
    int cvec = scol[li];                           // up to 64 col indices, one load

    const int nb8 = (nb + 7) & ~7;                 // scalar, <= 64

    float dlA[8]; uint huA[8];
    float dlB[8]; uint huB[8];

    GAT_LOAD8(dlA, huA, 0)
    for (int j0 = 0; j0 < nb8; j0 += 16) {
      if (j0 + 8 < nb8)  GAT_LOAD8(dlB, huB, j0 + 8)
      GAT_CONS8(dlA, huA, j0)
      if (j0 + 16 < nb8) GAT_LOAD8(dlA, huA, j0 + 16)
      if (j0 + 8 < nb8)  GAT_CONS8(dlB, huB, j0 + 8)
    }
  }

  float inv = 1.f / z;
  *(float2*)(out + (size_t)wid * 128 + lane * 2) = make_float2(ax * inv, ay * inv);
}

extern "C" void kernel_launch(void* const* d_in, const int* in_sizes, int n_in,
                              void* d_out, int out_size, void* d_ws, size_t ws_size,
                              hipStream_t stream) {
  const float* x    = (const float*)d_in[0];
  const int*   ei   = (const int*)d_in[1];
  const float* W    = (const float*)d_in[2];
  const float* srcA = (const float*)d_in[3];
  const float* dstA = (const float*)d_in[4];
  float* out = (float*)d_out;
  const int N = in_sizes[0] / 128;
  const int E = in_sizes[1] / 2;

  // workspace layout
  ushort* hbuf = (ushort*)d_ws;                       // N*128 bf16
  float* s  = (float*)(hbuf + (size_t)N * 128);       // N*8
  float* dv = s + (size_t)N * 8;                      // N*8
  ushort* wbf = (ushort*)(dv + (size_t)N * 8);        // 36*64*8 bf16 = 36864 B
  int* count   = (int*)((char*)wbf + 36864);          // N
  int* offsets = count + N;                           // N+1
  int* cursor  = offsets + (N + 1);                   // N
  int* partial = cursor + N;                          // 1024
  int* flag    = partial + 1024;                      // 4 (padded)
  int* scol    = flag + 4;                            // E+N
  int* rank    = scol + (E + N);                      // E (optional)

  const size_t need_rank = (size_t)((char*)(rank + E) - (char*)d_ws);
  const int userank = (ws_size >= need_rank) ? 1 : 0;

  const int nchunks = (N + 63) / 64;

  (void)hipMemsetAsync(count, 0, (size_t)N * sizeof(int), stream);
  gat_prep<<<9, 256, 0, stream>>>(W, srcA, dstA, wbf);
  gat_gemm_mfma<<<512, 256, 0, stream>>>(x, wbf, hbuf, s, dv, N, nchunks);
  gat_detect<<<1, 256, 0, stream>>>(ei, E, flag);
  gat_hist<<<2048, 256, 0, stream>>>(ei, E, flag, count, rank, userank);
  const int nb = (N + 1023) / 1024;
  gat_scan_part<<<nb, 256, 0, stream>>>(count, N, partial);
  gat_scan_mid<<<1, 1024, 0, stream>>>(partial, nb);
  gat_scan_final<<<nb, 256, 0, stream>>>(count, N, partial, offsets, cursor, E + N);
  if (userank)
    gat_scatter_rank<<<2048, 256, 0, stream>>>(ei, E, N, flag, offsets, count, rank, scol);
  else
    gat_scatter<<<2048, 256, 0, stream>>>(ei, E, N, flag, cursor, scol);
  gat_agg<<<(N + 3) / 4, 256, 0, stream>>>((const uint*)hbuf, s, dv, offsets, scol, out, N);
}

// Round 9
// 202.868 us; speedup vs baseline: 2.6079x; 1.0654x over previous
//
#include <hip/hip_runtime.h>
#include <hip/hip_bf16.h>
#include <math.h>

#define NEG_SLOPE 0.2f

typedef __attribute__((ext_vector_type(8))) short short8v;
typedef __attribute__((ext_vector_type(4))) float f32x4;

// ---------------- prep: zero count + pack B fragments [W^T | Ps | Pd] bf16 ----
__global__ __launch_bounds__(256) void gat_prep(
    const float* __restrict__ W, const float* __restrict__ srcA,
    const float* __restrict__ dstA, ushort* __restrict__ wbf,
    int* __restrict__ count, int N)
{
  for (int i = blockIdx.x * 256 + threadIdx.x; i < N; i += gridDim.x * 256)
    count[i] = 0;

  int tid = blockIdx.x * 256 + threadIdx.x;  // wbf built by first 2304 threads
  if (tid >= 36 * 64) return;
  int frag = tid >> 6, lane = tid & 63;
  int nt = frag >> 2, ks = frag & 3;
  int kbase = ks * 32 + (lane >> 4) * 8;
  ushort v[8];
  if (nt < 8) {
    int r = nt * 16 + (lane & 15);   // output col n -> W row
#pragma unroll
    for (int j = 0; j < 8; ++j)
      v[j] = __bfloat16_as_ushort(__float2bfloat16(W[(size_t)r * 128 + kbase + j]));
  } else {
    int n = lane & 15;
    int hd = n & 7;
    const float* av = (n < 8) ? srcA : dstA;
#pragma unroll
    for (int j = 0; j < 8; ++j) {
      float acc = 0.f;
      int k = kbase + j;
      for (int d = 0; d < 16; ++d)
        acc += W[(size_t)(hd * 16 + d) * 128 + k] * av[hd * 16 + d];
      v[j] = __bfloat16_as_ushort(__float2bfloat16(acc));
    }
  }
  ushort* dst = wbf + ((size_t)frag * 64 + lane) * 8;
#pragma unroll
  for (int j = 0; j < 8; ++j) dst[j] = v[j];
}

// ---------------- fused: MFMA GEMM (1/5 of blocks) + edge histogram (4/5) ----
// gemm: [h | s | dv] = x * [W^T | Ps | Pd]; hist: count[row]++, rank[i]=old.
__global__ __launch_bounds__(256, 2) void gat_gemm_hist(
    const float* __restrict__ x, const ushort* __restrict__ wbf,
    ushort* __restrict__ hb, float* __restrict__ s, float* __restrict__ dv,
    int N, int nchunks, int G1,
    const int* __restrict__ ei, int E, int* __restrict__ count,
    int* __restrict__ rank, int userank)
{
  const int q = (int)blockIdx.x / 5;
  const int r5 = (int)blockIdx.x % 5;
  if (r5 == 0) {
    // ---- GEMM block q of G1 ----
    const int wave = threadIdx.x >> 6, lane = threadIdx.x & 63;
    const int lrow = lane & 15, lkg = lane >> 4;

    short8v b[36];
    const short8v* wv = (const short8v*)wbf;
#pragma unroll
    for (int f = 0; f < 36; ++f) b[f] = wv[(size_t)f * 64 + lane];

    for (int chunk = q; chunk < nchunks; chunk += G1) {
      const int r0 = chunk * 64 + wave * 16;
      int arow = r0 + lrow; if (arow > N - 1) arow = N - 1;
      const float* xr = x + (size_t)arow * 128 + lkg * 8;

      f32x4 acc[9];
#pragma unroll
      for (int t = 0; t < 9; ++t) acc[t] = (f32x4){0.f, 0.f, 0.f, 0.f};

#pragma unroll
      for (int ks = 0; ks < 4; ++ks) {
        float4 x0 = *(const float4*)(xr + ks * 32);
        float4 x1 = *(const float4*)(xr + ks * 32 + 4);
        short8v a;
        a[0] = (short)__bfloat16_as_ushort(__float2bfloat16(x0.x));
        a[1] = (short)__bfloat16_as_ushort(__float2bfloat16(x0.y));
        a[2] = (short)__bfloat16_as_ushort(__float2bfloat16(x0.z));
        a[3] = (short)__bfloat16_as_ushort(__float2bfloat16(x0.w));
        a[4] = (short)__bfloat16_as_ushort(__float2bfloat16(x1.x));
        a[5] = (short)__bfloat16_as_ushort(__float2bfloat16(x1.y));
        a[6] = (short)__bfloat16_as_ushort(__float2bfloat16(x1.z));
        a[7] = (short)__bfloat16_as_ushort(__float2bfloat16(x1.w));
#pragma unroll
        for (int t = 0; t < 9; ++t)
          acc[t] = __builtin_amdgcn_mfma_f32_16x16x32_bf16(a, b[t * 4 + ks], acc[t], 0, 0, 0);
      }

      const int rbase = r0 + lkg * 4;  // C/D: row = (lane>>4)*4 + reg, col = lane&15
#pragma unroll
      for (int t = 0; t < 8; ++t) {
#pragma unroll
        for (int r = 0; r < 4; ++r) {
          int row = rbase + r;
          if (row < N)
            hb[(size_t)row * 128 + t * 16 + lrow] =
                __bfloat16_as_ushort(__float2bfloat16(acc[t][r]));
        }
      }
#pragma unroll
      for (int r = 0; r < 4; ++r) {
        int row = rbase + r;
        if (row < N) {
          if (lrow < 8) s[(size_t)row * 8 + lrow] = acc[8][r];
          else          dv[(size_t)row * 8 + (lrow - 8)] = acc[8][r];
        }
      }
    }
  } else {
    // ---- hist block (q*4 + r5-1) of 4*G1 ----
    __shared__ int sh64;
    if (threadIdx.x == 0) sh64 = 1;
    __syncthreads();
    if (ei[2 * threadIdx.x + 1] != 0) sh64 = 0;  // int32 layout -> some odd word != 0
    __syncthreads();
    const int is64 = sh64;

    const int hb_id = q * 4 + (r5 - 1);
    const int nhb = 4 * G1;
    int i = hb_id * 256 + threadIdx.x;
    const int stride = nhb * 256;
    for (; i < E; i += stride) {
      int r = is64 ? ei[2 * i] : ei[i];
      int old = atomicAdd(&count[r], 1);
      if (userank) rank[i] = old;
    }
  }
}

// ---------------- 2-level exclusive scan of (count[n] + 1) ----------------
__global__ __launch_bounds__(256) void gat_scan_part(
    const int* __restrict__ count, int N, int* __restrict__ partial)
{
  __shared__ int sm[256];
  int base = blockIdx.x * 1024;
  int tsum = 0;
  for (int i = threadIdx.x; i < 1024; i += 256) {
    int idx = base + i;
    if (idx < N) tsum += count[idx] + 1;  // +1 = self loop
  }
  sm[threadIdx.x] = tsum;
  __syncthreads();
  for (int off = 128; off > 0; off >>= 1) {
    if (threadIdx.x < off) sm[threadIdx.x] += sm[threadIdx.x + off];
    __syncthreads();
  }
  if (threadIdx.x == 0) partial[blockIdx.x] = sm[0];
}

__global__ __launch_bounds__(1024) void gat_scan_mid(int* __restrict__ partial, int nb)
{
  __shared__ int sm[1024];
  int t = threadIdx.x;
  int v = (t < nb) ? partial[t] : 0;
  sm[t] = v;
  __syncthreads();
  int acc = v;
  for (int off = 1; off < 1024; off <<= 1) {
    int other = (t >= off) ? sm[t - off] : 0;
    __syncthreads();
    acc += other;
    sm[t] = acc;
    __syncthreads();
  }
  if (t < nb) partial[t] = acc - v;  // exclusive
}

__global__ __launch_bounds__(256) void gat_scan_final(
    const int* __restrict__ count, int N, const int* __restrict__ partial,
    int* __restrict__ offsets, int* __restrict__ cursor, int total)
{
  __shared__ int sm[256];
  int base = blockIdx.x * 1024 + threadIdx.x * 4;
  int v[4];
  int tsum = 0;
#pragma unroll
  for (int j = 0; j < 4; ++j) {
    int idx = base + j;
    v[j] = (idx < N) ? (count[idx] + 1) : 0;
    tsum += v[j];
  }
  sm[threadIdx.x] = tsum;
  __syncthreads();
  int acc = tsum;
  for (int off = 1; off < 256; off <<= 1) {
    int other = (threadIdx.x >= off) ? sm[threadIdx.x - off] : 0;
    __syncthreads();
    acc += other;
    sm[threadIdx.x] = acc;
    __syncthreads();
  }
  int ex = acc - tsum + partial[blockIdx.x];
#pragma unroll
  for (int j = 0; j < 4; ++j) {
    int idx = base + j;
    if (idx < N) { offsets[idx] = ex; cursor[idx] = ex; ex += v[j]; }
  }
  if (blockIdx.x == 0 && threadIdx.x == 0) offsets[N] = total;
}

// ---------------- atomic-free scatter using precomputed ranks ----------------
__global__ __launch_bounds__(256) void gat_scatter_rank(
    const int* __restrict__ ei, int E, int N,
    const int* __restrict__ offsets, const int* __restrict__ count,
    const int* __restrict__ rank, int* __restrict__ scol)
{
  __shared__ int sh64;
  if (threadIdx.x == 0) sh64 = 1;
  __syncthreads();
  if (ei[2 * threadIdx.x + 1] != 0) sh64 = 0;
  __syncthreads();
  const int is64 = sh64;

  int i = blockIdx.x * 256 + threadIdx.x;
  const int stride = gridDim.x * 256;
  const int total = E + N;
  for (; i < total; i += stride) {
    int pos, c;
    if (i < E) {
      int r;
      if (is64) { r = ei[2 * i]; c = ei[2 * (E + i)]; }
      else      { r = ei[i];     c = ei[E + i]; }
      pos = offsets[r] + rank[i];
    } else {
      int r = i - E; c = r;                 // self loop -> last slot of row
      pos = offsets[r] + count[r];
    }
    scol[pos] = c;
  }
}

// ---------------- fallback: atomic-cursor scatter (if ws too small) ----------
__global__ __launch_bounds__(256) void gat_scatter(
    const int* __restrict__ ei, int E, int N,
    int* __restrict__ cursor, int* __restrict__ scol)
{
  __shared__ int sh64;
  if (threadIdx.x == 0) sh64 = 1;
  __syncthreads();
  if (ei[2 * threadIdx.x + 1] != 0) sh64 = 0;
  __syncthreads();
  const int is64 = sh64;

  int i = blockIdx.x * 256 + threadIdx.x;
  const int stride = gridDim.x * 256;
  const int total = E + N;
  for (; i < total; i += stride) {
    int r, c;
    if (i < E) {
      if (is64) { r = ei[2 * i]; c = ei[2 * (E + i)]; }
      else      { r = ei[i];     c = ei[E + i]; }
    } else {
      r = i - E; c = r;  // self loop
    }
    int pos = atomicAdd(&cursor[r], 1);
    scol[pos] = c;
  }
}

// ---------------- per-row softmax + SpMM, one wave per row ----------------
// 4 edges per wave iteration: lane = 16*g + t; group g handles edge (quad*4+g),
// lane covers h dims 8t..8t+7 via one dwordx4. exp redundancy 8x -> 2x.
// Pipeline: scol 2 quads ahead, dv/h gathers 1 quad ahead (no load-fed
// address in the same iteration). Cross-g reduce via shfl_xor(16,32).
__global__ __launch_bounds__(256) void gat_agg(
    const uint* __restrict__ hb, const float* __restrict__ s, const float* __restrict__ dv,
    const int* __restrict__ offsets, const int* __restrict__ scol,
    float* __restrict__ out, int N)
{
  int wid = (int)((blockIdx.x * 256 + threadIdx.x) >> 6);
  int lane = threadIdx.x & 63;
  if (wid >= N) return;
  const int g = lane >> 4;          // edge slot within quad
  const int t = lane & 15;          // dims 8t..8t+7
  const int head = t >> 1;
  const int beg = __builtin_amdgcn_readfirstlane(offsets[wid]);
  const int end = __builtin_amdgcn_readfirstlane(offsets[wid + 1]);  // >= beg+1
  const float sl = s[wid * 8 + head];

  const char* hbp = (const char*)hb;
  const char* dvp = (const char*)dv;
  const uint hoff = (uint)t * 16u;
  const uint doff = (uint)head * 4u;

  float z = 0.f;
  float a0 = 0, a1 = 0, a2 = 0, a3 = 0, a4 = 0, a5 = 0, a6 = 0, a7 = 0;

  const int nq = (end - beg + 3) >> 2;
  const int lasti = end - 1;

  // prologue: scol for quads 0 and 1; gathers for quad 0
  int iA = beg + g;       iA = iA < end ? iA : lasti;
  int iB = beg + 4 + g;   iB = iB < end ? iB : lasti;
  int cA = scol[iA];
  int cB = scol[iB];
  float dlA = *(const float*)(dvp + ((uint)cA * 32u + doff));
  uint4 huA = *(const uint4*)(hbp + ((uint)cA * 256u + hoff));

  for (int j = 0; j < nq; ++j) {
    // scol for quad j+2 (2 iterations of slack)
    int iC = beg + 4 * (j + 2) + g; iC = iC < end ? iC : lasti;
    int cC = scol[iC];
    // gathers for quad j+1 (cB loaded >= 1 iteration ago)
    float dlB = *(const float*)(dvp + ((uint)cB * 32u + doff));
    uint4 huB = *(const uint4*)(hbp + ((uint)cB * 256u + hoff));

    // consume quad j
    float e = sl + dlA;
    e = fmaxf(e, NEG_SLOPE * e);
    float w = (beg + 4 * j + g < end) ? __expf(e) : 0.f;
    z += w;
    a0 = fmaf(w, __uint_as_float(huA.x << 16), a0);
    a1 = fmaf(w, __uint_as_float(huA.x & 0xFFFF0000u), a1);
    a2 = fmaf(w, __uint_as_float(huA.y << 16), a2);
    a3 = fmaf(w, __uint_as_float(huA.y & 0xFFFF0000u), a3);
    a4 = fmaf(w, __uint_as_float(huA.z << 16), a4);
    a5 = fmaf(w, __uint_as_float(huA.z & 0xFFFF0000u), a5);
    a6 = fmaf(w, __uint_as_float(huA.w << 16), a6);
    a7 = fmaf(w, __uint_as_float(huA.w & 0xFFFF0000u), a7);

    cB = cC; dlA = dlB; huA = huB;
  }

  // reduce across the 4 edge groups (lanes t, 16+t, 32+t, 48+t)
  a0 += __shfl_xor(a0, 16, 64); a0 += __shfl_xor(a0, 32, 64);
  a1 += __shfl_xor(a1, 16, 64); a1 += __shfl_xor(a1, 32, 64);
  a2 += __shfl_xor(a2, 16, 64); a2 += __shfl_xor(a2, 32, 64);
  a3 += __shfl_xor(a3, 16, 64); a3 += __shfl_xor(a3, 32, 64);
  a4 += __shfl_xor(a4, 16, 64); a4 += __shfl_xor(a4, 32, 64);
  a5 += __shfl_xor(a5, 16, 64); a5 += __shfl_xor(a5, 32, 64);
  a6 += __shfl_xor(a6, 16, 64); a6 += __shfl_xor(a6, 32, 64);
  a7 += __shfl_xor(a7, 16, 64); a7 += __shfl_xor(a7, 32, 64);
  z  += __shfl_xor(z, 16, 64);  z  += __shfl_xor(z, 32, 64);

  float inv = 1.f / z;
  if (lane < 16) {
    float4* op = (float4*)(out + (size_t)wid * 128 + t * 8);
    op[0] = make_float4(a0 * inv, a1 * inv, a2 * inv, a3 * inv);
    op[1] = make_float4(a4 * inv, a5 * inv, a6 * inv, a7 * inv);
  }
}

extern "C" void kernel_launch(void* const* d_in, const int* in_sizes, int n_in,
                              void* d_out, int out_size, void* d_ws, size_t ws_size,
                              hipStream_t stream) {
  const float* x    = (const float*)d_in[0];
  const int*   ei   = (const int*)d_in[1];
  const float* W    = (const float*)d_in[2];
  const float* srcA = (const float*)d_in[3];
  const float* dstA = (const float*)d_in[4];
  float* out = (float*)d_out;
  const int N = in_sizes[0] / 128;
  const int E = in_sizes[1] / 2;

  // workspace layout
  ushort* hbuf = (ushort*)d_ws;                       // N*128 bf16
  float* s  = (float*)(hbuf + (size_t)N * 128);       // N*8
  float* dv = s + (size_t)N * 8;                      // N*8
  ushort* wbf = (ushort*)(dv + (size_t)N * 8);        // 36*64*8 bf16 = 36864 B
  int* count   = (int*)((char*)wbf + 36864);          // N
  int* offsets = count + N;                           // N+1
  int* cursor  = offsets + (N + 1);                   // N
  int* partial = cursor + N;                          // 1024
  int* scol    = partial + 1024;                      // E+N
  int* rank    = scol + (E + N);                      // E (optional)

  const size_t need_rank = (size_t)((char*)(rank + E) - (char*)d_ws);
  const int userank = (ws_size >= need_rank) ? 1 : 0;

  const int nchunks = (N + 63) / 64;
  const int G1 = 512;

  gat_prep<<<2048, 256, 0, stream>>>(W, srcA, dstA, wbf, count, N);
  gat_gemm_hist<<<5 * G1, 256, 0, stream>>>(x, wbf, hbuf, s, dv, N, nchunks, G1,
                                            ei, E, count, rank, userank);
  const int nb = (N + 1023) / 1024;
  gat_scan_part<<<nb, 256, 0, stream>>>(count, N, partial);
  gat_scan_mid<<<1, 1024, 0, stream>>>(partial, nb);
  gat_scan_final<<<nb, 256, 0, stream>>>(count, N, partial, offsets, cursor, E + N);
  if (userank)
    gat_scatter_rank<<<2048, 256, 0, stream>>>(ei, E, N, offsets, count, rank, scol);
  else
    gat_scatter<<<2048, 256, 0, stream>>>(ei, E, N, cursor, scol);
  gat_agg<<<(N + 3) / 4, 256, 0, stream>>>((const uint*)hbuf, s, dv, offsets, scol, out, N);
}

// Round 10
// 202.399 us; speedup vs baseline: 2.6140x; 1.0023x over previous
//
#include <hip/hip_runtime.h>
#include <hip/hip_bf16.h>
#include <math.h>

#define NEG_SLOPE 0.2f

typedef __attribute__((ext_vector_type(8))) short short8v;
typedef __attribute__((ext_vector_type(4))) float f32x4;

// ---------------- prep: zero count + pack B fragments [W^T | Ps | Pd] bf16 ----
__global__ __launch_bounds__(256) void gat_prep(
    const float* __restrict__ W, const float* __restrict__ srcA,
    const float* __restrict__ dstA, ushort* __restrict__ wbf,
    int* __restrict__ count, int N)
{
  for (int i = blockIdx.x * 256 + threadIdx.x; i < N; i += gridDim.x * 256)
    count[i] = 0;

  int tid = blockIdx.x * 256 + threadIdx.x;  // wbf built by first 2304 threads
  if (tid >= 36 * 64) return;
  int frag = tid >> 6, lane = tid & 63;
  int nt = frag >> 2, ks = frag & 3;
  int kbase = ks * 32 + (lane >> 4) * 8;
  ushort v[8];
  if (nt < 8) {
    int r = nt * 16 + (lane & 15);   // output col n -> W row
#pragma unroll
    for (int j = 0; j < 8; ++j)
      v[j] = __bfloat16_as_ushort(__float2bfloat16(W[(size_t)r * 128 + kbase + j]));
  } else {
    int n = lane & 15;
    int hd = n & 7;
    const float* av = (n < 8) ? srcA : dstA;
#pragma unroll
    for (int j = 0; j < 8; ++j) {
      float acc = 0.f;
      int k = kbase + j;
      for (int d = 0; d < 16; ++d)
        acc += W[(size_t)(hd * 16 + d) * 128 + k] * av[hd * 16 + d];
      v[j] = __bfloat16_as_ushort(__float2bfloat16(acc));
    }
  }
  ushort* dst = wbf + ((size_t)frag * 64 + lane) * 8;
#pragma unroll
  for (int j = 0; j < 8; ++j) dst[j] = v[j];
}

// ---------------- fused: MFMA GEMM (1/5 of blocks) + edge histogram (4/5) ----
__global__ __launch_bounds__(256, 2) void gat_gemm_hist(
    const float* __restrict__ x, const ushort* __restrict__ wbf,
    ushort* __restrict__ hb, float* __restrict__ s, float* __restrict__ dv,
    int N, int nchunks, int G1,
    const int* __restrict__ ei, int E, int* __restrict__ count,
    int* __restrict__ rank, int userank)
{
  const int q = (int)blockIdx.x / 5;
  const int r5 = (int)blockIdx.x % 5;
  if (r5 == 0) {
    // ---- GEMM block q of G1 ----
    const int wave = threadIdx.x >> 6, lane = threadIdx.x & 63;
    const int lrow = lane & 15, lkg = lane >> 4;

    short8v b[36];
    const short8v* wv = (const short8v*)wbf;
#pragma unroll
    for (int f = 0; f < 36; ++f) b[f] = wv[(size_t)f * 64 + lane];

    for (int chunk = q; chunk < nchunks; chunk += G1) {
      const int r0 = chunk * 64 + wave * 16;
      int arow = r0 + lrow; if (arow > N - 1) arow = N - 1;
      const float* xr = x + (size_t)arow * 128 + lkg * 8;

      f32x4 acc[9];
#pragma unroll
      for (int t = 0; t < 9; ++t) acc[t] = (f32x4){0.f, 0.f, 0.f, 0.f};

#pragma unroll
      for (int ks = 0; ks < 4; ++ks) {
        float4 x0 = *(const float4*)(xr + ks * 32);
        float4 x1 = *(const float4*)(xr + ks * 32 + 4);
        short8v a;
        a[0] = (short)__bfloat16_as_ushort(__float2bfloat16(x0.x));
        a[1] = (short)__bfloat16_as_ushort(__float2bfloat16(x0.y));
        a[2] = (short)__bfloat16_as_ushort(__float2bfloat16(x0.z));
        a[3] = (short)__bfloat16_as_ushort(__float2bfloat16(x0.w));
        a[4] = (short)__bfloat16_as_ushort(__float2bfloat16(x1.x));
        a[5] = (short)__bfloat16_as_ushort(__float2bfloat16(x1.y));
        a[6] = (short)__bfloat16_as_ushort(__float2bfloat16(x1.z));
        a[7] = (short)__bfloat16_as_ushort(__float2bfloat16(x1.w));
#pragma unroll
        for (int t = 0; t < 9; ++t)
          acc[t] = __builtin_amdgcn_mfma_f32_16x16x32_bf16(a, b[t * 4 + ks], acc[t], 0, 0, 0);
      }

      const int rbase = r0 + lkg * 4;  // C/D: row = (lane>>4)*4 + reg, col = lane&15
#pragma unroll
      for (int t = 0; t < 8; ++t) {
#pragma unroll
        for (int r = 0; r < 4; ++r) {
          int row = rbase + r;
          if (row < N)
            hb[(size_t)row * 128 + t * 16 + lrow] =
                __bfloat16_as_ushort(__float2bfloat16(acc[t][r]));
        }
      }
#pragma unroll
      for (int r = 0; r < 4; ++r) {
        int row = rbase + r;
        if (row < N) {
          if (lrow < 8) s[(size_t)row * 8 + lrow] = acc[8][r];
          else          dv[(size_t)row * 8 + (lrow - 8)] = acc[8][r];
        }
      }
    }
  } else {
    // ---- hist block (q*4 + r5-1) of 4*G1 ----
    __shared__ int sh64;
    if (threadIdx.x == 0) sh64 = 1;
    __syncthreads();
    if (ei[2 * threadIdx.x + 1] != 0) sh64 = 0;  // int32 layout -> some odd word != 0
    __syncthreads();
    const int is64 = sh64;

    const int hb_id = q * 4 + (r5 - 1);
    const int nhb = 4 * G1;
    int i = hb_id * 256 + threadIdx.x;
    const int stride = nhb * 256;
    for (; i < E; i += stride) {
      int r = is64 ? ei[2 * i] : ei[i];
      int old = atomicAdd(&count[r], 1);
      if (userank) rank[i] = old;
    }
  }
}

// ---------------- 2-level exclusive scan of (count[n] + 1) ----------------
__global__ __launch_bounds__(256) void gat_scan_part(
    const int* __restrict__ count, int N, int* __restrict__ partial)
{
  __shared__ int sm[256];
  int base = blockIdx.x * 1024;
  int tsum = 0;
  for (int i = threadIdx.x; i < 1024; i += 256) {
    int idx = base + i;
    if (idx < N) tsum += count[idx] + 1;  // +1 = self loop
  }
  sm[threadIdx.x] = tsum;
  __syncthreads();
  for (int off = 128; off > 0; off >>= 1) {
    if (threadIdx.x < off) sm[threadIdx.x] += sm[threadIdx.x + off];
    __syncthreads();
  }
  if (threadIdx.x == 0) partial[blockIdx.x] = sm[0];
}

__global__ __launch_bounds__(1024) void gat_scan_mid(int* __restrict__ partial, int nb)
{
  __shared__ int sm[1024];
  int t = threadIdx.x;
  int v = (t < nb) ? partial[t] : 0;
  sm[t] = v;
  __syncthreads();
  int acc = v;
  for (int off = 1; off < 1024; off <<= 1) {
    int other = (t >= off) ? sm[t - off] : 0;
    __syncthreads();
    acc += other;
    sm[t] = acc;
    __syncthreads();
  }
  if (t < nb) partial[t] = acc - v;  // exclusive
}

__global__ __launch_bounds__(256) void gat_scan_final(
    const int* __restrict__ count, int N, const int* __restrict__ partial,
    int* __restrict__ offsets, int* __restrict__ cursor, int total)
{
  __shared__ int sm[256];
  int base = blockIdx.x * 1024 + threadIdx.x * 4;
  int v[4];
  int tsum = 0;
#pragma unroll
  for (int j = 0; j < 4; ++j) {
    int idx = base + j;
    v[j] = (idx < N) ? (count[idx] + 1) : 0;
    tsum += v[j];
  }
  sm[threadIdx.x] = tsum;
  __syncthreads();
  int acc = tsum;
  for (int off = 1; off < 256; off <<= 1) {
    int other = (threadIdx.x >= off) ? sm[threadIdx.x - off] : 0;
    __syncthreads();
    acc += other;
    sm[threadIdx.x] = acc;
    __syncthreads();
  }
  int ex = acc - tsum + partial[blockIdx.x];
#pragma unroll
  for (int j = 0; j < 4; ++j) {
    int idx = base + j;
    if (idx < N) { offsets[idx] = ex; cursor[idx] = ex; ex += v[j]; }
  }
  if (blockIdx.x == 0 && threadIdx.x == 0) offsets[N] = total;
}

// ---------------- atomic-free scatter using precomputed ranks ----------------
__global__ __launch_bounds__(256) void gat_scatter_rank(
    const int* __restrict__ ei, int E, int N,
    const int* __restrict__ offsets, const int* __restrict__ count,
    const int* __restrict__ rank, int* __restrict__ scol)
{
  __shared__ int sh64;
  if (threadIdx.x == 0) sh64 = 1;
  __syncthreads();
  if (ei[2 * threadIdx.x + 1] != 0) sh64 = 0;
  __syncthreads();
  const int is64 = sh64;

  int i = blockIdx.x * 256 + threadIdx.x;
  const int stride = gridDim.x * 256;
  const int total = E + N;
  for (; i < total; i += stride) {
    int pos, c;
    if (i < E) {
      int r;
      if (is64) { r = ei[2 * i]; c = ei[2 * (E + i)]; }
      else      { r = ei[i];     c = ei[E + i]; }
      pos = offsets[r] + rank[i];
    } else {
      int r = i - E; c = r;                 // self loop -> last slot of row
      pos = offsets[r] + count[r];
    }
    scol[pos] = c;
  }
}

// ---------------- fallback: atomic-cursor scatter (if ws too small) ----------
__global__ __launch_bounds__(256) void gat_scatter(
    const int* __restrict__ ei, int E, int N,
    int* __restrict__ cursor, int* __restrict__ scol)
{
  __shared__ int sh64;
  if (threadIdx.x == 0) sh64 = 1;
  __syncthreads();
  if (ei[2 * threadIdx.x + 1] != 0) sh64 = 0;
  __syncthreads();
  const int is64 = sh64;

  int i = blockIdx.x * 256 + threadIdx.x;
  const int stride = gridDim.x * 256;
  const int total = E + N;
  for (; i < total; i += stride) {
    int r, c;
    if (i < E) {
      if (is64) { r = ei[2 * i]; c = ei[2 * (E + i)]; }
      else      { r = ei[i];     c = ei[E + i]; }
    } else {
      r = i - E; c = r;  // self loop
    }
    int pos = atomicAdd(&cursor[r], 1);
    scol[pos] = c;
  }
}

// ---------------- per-row softmax + SpMM, one wave per row ----------------
// 4 edges per wave iteration: lane = 16*g + t; group g handles edge (quad*4+g),
// lane covers h dims 8t..8t+7 via one dwordx4.
// Depth-2 gather pipeline: gathers for quads j+1 AND j+2 in flight (8 edges,
// ~2.3 KB/wave outstanding); scol fetched 3 quads ahead. Consume of quad j
// uses data issued at iteration j-2.
__global__ __launch_bounds__(256) void gat_agg(
    const uint* __restrict__ hb, const float* __restrict__ s, const float* __restrict__ dv,
    const int* __restrict__ offsets, const int* __restrict__ scol,
    float* __restrict__ out, int N)
{
  int wid = (int)((blockIdx.x * 256 + threadIdx.x) >> 6);
  int lane = threadIdx.x & 63;
  if (wid >= N) return;
  const int g = lane >> 4;          // edge slot within quad
  const int t = lane & 15;          // dims 8t..8t+7
  const int head = t >> 1;
  const int beg = __builtin_amdgcn_readfirstlane(offsets[wid]);
  const int end = __builtin_amdgcn_readfirstlane(offsets[wid + 1]);  // >= beg+1
  const float sl = s[wid * 8 + head];

  const char* hbp = (const char*)hb;
  const char* dvp = (const char*)dv;
  const uint hoff = (uint)t * 16u;
  const uint doff = (uint)head * 4u;

  float z = 0.f;
  float a0 = 0, a1 = 0, a2 = 0, a3 = 0, a4 = 0, a5 = 0, a6 = 0, a7 = 0;

  const int nq = (end - beg + 3) >> 2;
  const int lasti = end - 1;

  // prologue: scol for quads 0,1,2; gathers for quads 0 and 1
  int iA = beg + g;       iA = iA < end ? iA : lasti;
  int iB = beg + 4 + g;   iB = iB < end ? iB : lasti;
  int iC = beg + 8 + g;   iC = iC < end ? iC : lasti;
  int cB = scol[iB];
  int cC = scol[iC];
  int cA = scol[iA];
  float dlA = *(const float*)(dvp + ((uint)cA * 32u + doff));
  uint4 huA = *(const uint4*)(hbp + ((uint)cA * 256u + hoff));
  float dlB = *(const float*)(dvp + ((uint)cB * 32u + doff));
  uint4 huB = *(const uint4*)(hbp + ((uint)cB * 256u + hoff));

  for (int j = 0; j < nq; ++j) {
    // scol for quad j+3 (3 iterations of slack)
    int iD = beg + 4 * (j + 3) + g; iD = iD < end ? iD : lasti;
    int cD = scol[iD];
    // gathers for quad j+2 (cC loaded >= 2 iterations ago)
    float dlC = *(const float*)(dvp + ((uint)cC * 32u + doff));
    uint4 huC = *(const uint4*)(hbp + ((uint)cC * 256u + hoff));

    // consume quad j (issued 2 iterations ago)
    float e = sl + dlA;
    e = fmaxf(e, NEG_SLOPE * e);
    float w = (beg + 4 * j + g < end) ? __expf(e) : 0.f;
    z += w;
    a0 = fmaf(w, __uint_as_float(huA.x << 16), a0);
    a1 = fmaf(w, __uint_as_float(huA.x & 0xFFFF0000u), a1);
    a2 = fmaf(w, __uint_as_float(huA.y << 16), a2);
    a3 = fmaf(w, __uint_as_float(huA.y & 0xFFFF0000u), a3);
    a4 = fmaf(w, __uint_as_float(huA.z << 16), a4);
    a5 = fmaf(w, __uint_as_float(huA.z & 0xFFFF0000u), a5);
    a6 = fmaf(w, __uint_as_float(huA.w << 16), a6);
    a7 = fmaf(w, __uint_as_float(huA.w & 0xFFFF0000u), a7);

    // rotate
    dlA = dlB; huA = huB;
    dlB = dlC; huB = huC;
    cC = cD;
  }

  // reduce across the 4 edge groups (lanes t, 16+t, 32+t, 48+t)
  a0 += __shfl_xor(a0, 16, 64); a0 += __shfl_xor(a0, 32, 64);
  a1 += __shfl_xor(a1, 16, 64); a1 += __shfl_xor(a1, 32, 64);
  a2 += __shfl_xor(a2, 16, 64); a2 += __shfl_xor(a2, 32, 64);
  a3 += __shfl_xor(a3, 16, 64); a3 += __shfl_xor(a3, 32, 64);
  a4 += __shfl_xor(a4, 16, 64); a4 += __shfl_xor(a4, 32, 64);
  a5 += __shfl_xor(a5, 16, 64); a5 += __shfl_xor(a5, 32, 64);
  a6 += __shfl_xor(a6, 16, 64); a6 += __shfl_xor(a6, 32, 64);
  a7 += __shfl_xor(a7, 16, 64); a7 += __shfl_xor(a7, 32, 64);
  z  += __shfl_xor(z, 16, 64);  z  += __shfl_xor(z, 32, 64);

  float inv = 1.f / z;
  if (lane < 16) {
    float4* op = (float4*)(out + (size_t)wid * 128 + t * 8);
    op[0] = make_float4(a0 * inv, a1 * inv, a2 * inv, a3 * inv);
    op[1] = make_float4(a4 * inv, a5 * inv, a6 * inv, a7 * inv);
  }
}

extern "C" void kernel_launch(void* const* d_in, const int* in_sizes, int n_in,
                              void* d_out, int out_size, void* d_ws, size_t ws_size,
                              hipStream_t stream) {
  const float* x    = (const float*)d_in[0];
  const int*   ei   = (const int*)d_in[1];
  const float* W    = (const float*)d_in[2];
  const float* srcA = (const float*)d_in[3];
  const float* dstA = (const float*)d_in[4];
  float* out = (float*)d_out;
  const int N = in_sizes[0] / 128;
  const int E = in_sizes[1] / 2;

  // workspace layout
  ushort* hbuf = (ushort*)d_ws;                       // N*128 bf16
  float* s  = (float*)(hbuf + (size_t)N * 128);       // N*8
  float* dv = s + (size_t)N * 8;                      // N*8
  ushort* wbf = (ushort*)(dv + (size_t)N * 8);        // 36*64*8 bf16 = 36864 B
  int* count   = (int*)((char*)wbf + 36864);          // N
  int* offsets = count + N;                           // N+1
  int* cursor  = offsets + (N + 1);                   // N
  int* partial = cursor + N;                          // 1024
  int* scol    = partial + 1024;                      // E+N
  int* rank    = scol + (E + N);                      // E (optional)

  const size_t need_rank = (size_t)((char*)(rank + E) - (char*)d_ws);
  const int userank = (ws_size >= need_rank) ? 1 : 0;

  const int nchunks = (N + 63) / 64;
  const int G1 = 512;

  gat_prep<<<2048, 256, 0, stream>>>(W, srcA, dstA, wbf, count, N);
  gat_gemm_hist<<<5 * G1, 256, 0, stream>>>(x, wbf, hbuf, s, dv, N, nchunks, G1,
                                            ei, E, count, rank, userank);
  const int nb = (N + 1023) / 1024;
  gat_scan_part<<<nb, 256, 0, stream>>>(count, N, partial);
  gat_scan_mid<<<1, 1024, 0, stream>>>(partial, nb);
  gat_scan_final<<<nb, 256, 0, stream>>>(count, N, partial, offsets, cursor, E + N);
  if (userank)
    gat_scatter_rank<<<2048, 256, 0, stream>>>(ei, E, N, offsets, count, rank, scol);
  else
    gat_scatter<<<2048, 256, 0, stream>>>(ei, E, N, cursor, scol);
  gat_agg<<<(N + 3) / 4, 256, 0, stream>>>((const uint*)hbuf, s, dv, offsets, scol, out, N);
}